// Round 1
// baseline (1338.149 us; speedup 1.0000x reference)
//
#include <hip/hip_runtime.h>
#include <hip/hip_bf16.h>

#define N_NODES 50000
#define N_EDGES 800000
#define E_TOT   850000
#define NB      1024
#define NODE_DIM 21
#define ESM_DIM 480
#define HD      128

// ---------------- CSR build ----------------

__global__ void count_edges(const int* __restrict__ ei, int* __restrict__ deg) {
    int e = blockIdx.x * 256 + threadIdx.x;
    if (e >= E_TOT) return;
    int d = (e < N_EDGES) ? ei[N_EDGES + e] : (e - N_EDGES);
    atomicAdd(&deg[d], 1);
}

__global__ void scan_kernel(const int* __restrict__ deg, int* __restrict__ row_ptr,
                            int* __restrict__ cursor) {
    __shared__ int buf[1024];
    __shared__ int carry;
    int t = threadIdx.x;
    if (t == 0) carry = 0;
    __syncthreads();
    for (int base = 0; base < N_NODES; base += 1024) {
        int i = base + t;
        int v = (i < N_NODES) ? deg[i] : 0;
        buf[t] = v;
        __syncthreads();
        for (int off = 1; off < 1024; off <<= 1) {
            int add = (t >= off) ? buf[t - off] : 0;
            __syncthreads();
            buf[t] += add;
            __syncthreads();
        }
        int excl = buf[t] - v;
        if (i < N_NODES) {
            int rp = carry + excl;
            row_ptr[i] = rp;
            cursor[i] = rp;
        }
        __syncthreads();
        if (t == 1023) carry += buf[1023];
        __syncthreads();
    }
    if (t == 0) row_ptr[N_NODES] = carry;
}

__global__ void fill_edges(const int* __restrict__ ei, int* __restrict__ cursor,
                           int* __restrict__ csr_src) {
    int e = blockIdx.x * 256 + threadIdx.x;
    if (e >= E_TOT) return;
    int s, d;
    if (e < N_EDGES) { s = ei[e]; d = ei[N_EDGES + e]; }
    else             { s = d = e - N_EDGES; }
    int pos = atomicAdd(&cursor[d], 1);
    csr_src[pos] = s;
}

// batch is sorted; compute graph start offsets (start[B]=N), handles empty graphs
__global__ void graph_bounds(const int* __restrict__ batch, int* __restrict__ start) {
    int i = blockIdx.x * 256 + threadIdx.x;
    if (i >= N_NODES) return;
    int b = batch[i];
    int bp = (i == 0) ? -1 : batch[i - 1];
    for (int g = bp + 1; g <= b; ++g) start[g] = i;
    if (i == N_NODES - 1)
        for (int g = b + 1; g <= NB; ++g) start[g] = N_NODES;
}

// ---------------- GAT1 linear: [N,21]@[21x128]^T ----------------

__global__ void matmul_gat1(const float* __restrict__ X, const float* __restrict__ W,
                            float* __restrict__ out) {
    __shared__ float Xs[32][23];
    __shared__ float Ws[128][23];
    int t = threadIdx.x;
    int r0 = blockIdx.x * 32;
    for (int idx = t; idx < 128 * 21; idx += 256) Ws[idx / 21][idx % 21] = W[idx];
    for (int idx = t; idx < 32 * 21; idx += 256) {
        int r = idx / 21, k = idx % 21;
        Xs[r][k] = (r0 + r < N_NODES) ? X[(size_t)(r0 + r) * 21 + k] : 0.f;
    }
    __syncthreads();
    int f = t & 127, rsub = t >> 7;
    for (int r = rsub; r < 32; r += 2) {
        if (r0 + r >= N_NODES) break;
        float a = 0.f;
#pragma unroll
        for (int k = 0; k < 21; ++k) a += Xs[r][k] * Ws[f][k];
        out[(size_t)(r0 + r) * HD + f] = a;
    }
}

// ---------------- generic tiled matmul: out[M,F] = X[M,K] @ W[F,K]^T (+bias, relu) ----------------
// block 256 threads: 32 rows x 128 feats; grid.y = F/128; K multiple of 32

__global__ void matmul_tiled(const float* __restrict__ X, const float* __restrict__ W,
                             const float* __restrict__ bias, float* __restrict__ out,
                             int M, int K, int F, int act) {
    __shared__ float Xs[32][33];
    __shared__ float Ws[128][33];
    int t = threadIdx.x;
    int r0 = blockIdx.x * 32;
    int fb = blockIdx.y * 128;
    int f = t & 127, rsub = t >> 7;
    float acc[16];
#pragma unroll
    for (int i = 0; i < 16; ++i) acc[i] = 0.f;
    for (int kc = 0; kc < K; kc += 32) {
        int idx = t * 4;
        int xr = idx >> 5, xk = idx & 31;
        if (r0 + xr < M) {
            const float* p = &X[(size_t)(r0 + xr) * K + kc + xk];
            Xs[xr][xk] = p[0]; Xs[xr][xk + 1] = p[1]; Xs[xr][xk + 2] = p[2]; Xs[xr][xk + 3] = p[3];
        } else {
            Xs[xr][xk] = 0.f; Xs[xr][xk + 1] = 0.f; Xs[xr][xk + 2] = 0.f; Xs[xr][xk + 3] = 0.f;
        }
#pragma unroll
        for (int i = 0; i < 16; ++i) {
            int id2 = t + 256 * i;
            int wf = id2 >> 5, wk = id2 & 31;
            Ws[wf][wk] = W[(size_t)(fb + wf) * K + kc + wk];
        }
        __syncthreads();
#pragma unroll
        for (int rr = 0; rr < 16; ++rr) {
            int r = rsub + rr * 2;
            float a = 0.f;
#pragma unroll
            for (int k = 0; k < 32; ++k) a += Xs[r][k] * Ws[f][k];
            acc[rr] += a;
        }
        __syncthreads();
    }
    float bv = bias ? bias[fb + f] : 0.f;
    for (int rr = 0; rr < 16; ++rr) {
        int r = r0 + rsub + rr * 2;
        if (r < M) {
            float v = acc[rr] + bv;
            if (act) v = fmaxf(v, 0.f);
            out[(size_t)r * F + fb + f] = v;
        }
    }
}

// ---------------- per-node alphas: alpha = h_row . a ----------------

__global__ void alpha_kernel(const float* __restrict__ h, const float* __restrict__ asrc,
                             const float* __restrict__ adst, float* __restrict__ alpha_s,
                             float* __restrict__ alpha_d) {
    int w = (int)((blockIdx.x * (size_t)blockDim.x + threadIdx.x) >> 6);
    int lane = threadIdx.x & 63;
    if (w >= N_NODES) return;
    float2 hv = *(const float2*)&h[(size_t)w * HD + lane * 2];
    float2 as = *(const float2*)&asrc[lane * 2];
    float2 ad = *(const float2*)&adst[lane * 2];
    float s = hv.x * as.x + hv.y * as.y;
    float d = hv.x * ad.x + hv.y * ad.y;
    for (int off = 32; off; off >>= 1) {
        s += __shfl_down(s, off);
        d += __shfl_down(d, off);
    }
    if (lane == 0) { alpha_s[w] = s; alpha_d[w] = d; }
}

// ---------------- GAT aggregation (edge softmax by dst, no atomics) ----------------
// one wave per dst node; lane owns 2 features

__global__ void gat_agg(const float* __restrict__ h, const int* __restrict__ row_ptr,
                        const int* __restrict__ csr_src, const float* __restrict__ alpha_s,
                        const float* __restrict__ alpha_d, const float* __restrict__ bias,
                        float* __restrict__ out) {
    int w = (int)((blockIdx.x * (size_t)blockDim.x + threadIdx.x) >> 6);
    int lane = threadIdx.x & 63;
    if (w >= N_NODES) return;
    int rs = row_ptr[w], re = row_ptr[w + 1];
    float ad = alpha_d[w];
    // pass 1: segment max (lanes split edges)
    float m = -1e30f;
    for (int i = rs + lane; i < re; i += 64) {
        int s = csr_src[i];
        float e = alpha_s[s] + ad;
        e = (e > 0.f) ? e : 0.2f * e;
        m = fmaxf(m, e);
    }
    for (int off = 32; off; off >>= 1) m = fmaxf(m, __shfl_xor(m, off));
    // pass 2: whole wave walks edges; each lane accumulates 2 features
    float den = 0.f, ax = 0.f, ay = 0.f;
    for (int i = rs; i < re; ++i) {
        int s = csr_src[i];
        float e = alpha_s[s] + ad;
        e = (e > 0.f) ? e : 0.2f * e;
        float ex = __expf(e - m);
        den += ex;
        float2 hv = *(const float2*)&h[(size_t)s * HD + lane * 2];
        ax += ex * hv.x;
        ay += ex * hv.y;
    }
    float inv = 1.f / (den + 1e-16f);
    float2 bv = *(const float2*)&bias[lane * 2];
    float vx = fmaxf(ax * inv + bv.x, 0.f);
    float vy = fmaxf(ay * inv + bv.y, 0.f);
    *(float2*)&out[(size_t)w * HD + lane * 2] = make_float2(vx, vy);
}

// ---------------- mean pool per graph (batch sorted) ----------------

__global__ void pool_kernel(const float* __restrict__ h, const int* __restrict__ start,
                            float* __restrict__ z) {
    int w = (int)((blockIdx.x * (size_t)blockDim.x + threadIdx.x) >> 6);
    int lane = threadIdx.x & 63;
    if (w >= NB) return;
    int s0 = start[w], s1 = start[w + 1];
    float ax = 0.f, ay = 0.f;
    for (int n = s0; n < s1; ++n) {
        float2 hv = *(const float2*)&h[(size_t)n * HD + lane * 2];
        ax += hv.x; ay += hv.y;
    }
    float c = fmaxf((float)(s1 - s0), 1.f);
    *(float2*)&z[(size_t)w * 320 + lane * 2] = make_float2(ax / c, ay / c);
}

// ---------------- LSTM gates -> z cols [128,256) ----------------

__device__ __forceinline__ float sigmoidf_(float x) { return 1.f / (1.f + __expf(-x)); }

__global__ void lstm_gate(const float* __restrict__ gf, const float* __restrict__ gr,
                          const float* __restrict__ bhhf, const float* __restrict__ bhhr,
                          float* __restrict__ z) {
    int idx = blockIdx.x * 256 + threadIdx.x;
    if (idx >= NB * 128) return;
    int b = idx >> 7, jj = idx & 127;
    int dir = jj >> 6, j = jj & 63;
    const float* g = dir ? gr : gf;
    const float* bhh = dir ? bhhr : bhhf;
    float gi = g[(size_t)b * 256 + j]       + bhh[j];
    float gg = g[(size_t)b * 256 + 128 + j] + bhh[128 + j];
    float go = g[(size_t)b * 256 + 192 + j] + bhh[192 + j];
    float c = sigmoidf_(gi) * tanhf(gg);
    z[(size_t)b * 320 + 128 + jj] = sigmoidf_(go) * tanhf(c);
}

// ---------------- tab pre-BN linear ----------------

__global__ void tab_pre(const float* __restrict__ tf, const float* __restrict__ W,
                        const float* __restrict__ bias, float* __restrict__ out) {
    int idx = blockIdx.x * 256 + threadIdx.x;
    if (idx >= NB * 64) return;
    int b = idx >> 6, j = idx & 63;
    const float* x = &tf[(size_t)b * 7];
    const float* w = &W[(size_t)j * 7];
    float a = bias[j];
#pragma unroll
    for (int k = 0; k < 7; ++k) a += x[k] * w[k];
    out[idx] = a;
}

// ---------------- BatchNorm (training stats over 1024 rows) + relu ----------------
// one block (256 thr) per feature column

__global__ void bn_relu_cols(const float* __restrict__ in, int cols,
                             const float* __restrict__ g, const float* __restrict__ b,
                             float* __restrict__ out, int out_stride, int out_col0) {
    int j = blockIdx.x;
    int t = threadIdx.x;
    __shared__ float ssum[256], ssq[256];
    float vals[4];
    float s = 0.f, q = 0.f;
#pragma unroll
    for (int i = 0; i < 4; ++i) {
        float v = in[(size_t)(t + 256 * i) * cols + j];
        vals[i] = v; s += v; q += v * v;
    }
    ssum[t] = s; ssq[t] = q;
    __syncthreads();
    for (int off = 128; off; off >>= 1) {
        if (t < off) { ssum[t] += ssum[t + off]; ssq[t] += ssq[t + off]; }
        __syncthreads();
    }
    float mu = ssum[0] * (1.f / 1024.f);
    float var = ssq[0] * (1.f / 1024.f) - mu * mu;
    float sc = rsqrtf(var + 1e-5f) * g[j];
    float bb = b[j] - mu * sc;
#pragma unroll
    for (int i = 0; i < 4; ++i) {
        float v = vals[i] * sc + bb;
        out[(size_t)(t + 256 * i) * out_stride + out_col0 + j] = fmaxf(v, 0.f);
    }
}

// ---------------- final 128->1 ----------------

__global__ void final_kernel(const float* __restrict__ z2, const float* __restrict__ W,
                             const float* __restrict__ b, float* __restrict__ out) {
    int w = (int)((blockIdx.x * (size_t)blockDim.x + threadIdx.x) >> 6);
    int lane = threadIdx.x & 63;
    if (w >= NB) return;
    float2 zv = *(const float2*)&z2[(size_t)w * 128 + lane * 2];
    float2 wv = *(const float2*)&W[lane * 2];
    float s = zv.x * wv.x + zv.y * wv.y;
    for (int off = 32; off; off >>= 1) s += __shfl_down(s, off);
    if (lane == 0) out[w] = s + b[0];
}

// ---------------- launch ----------------

extern "C" void kernel_launch(void* const* d_in, const int* in_sizes, int n_in,
                              void* d_out, int out_size, void* d_ws, size_t ws_size,
                              hipStream_t stream) {
    const float* x        = (const float*)d_in[0];
    const int*   ei       = (const int*)d_in[1];
    const int*   batch    = (const int*)d_in[2];
    const float* esm      = (const float*)d_in[3];
    const float* tabf     = (const float*)d_in[4];
    const float* gat1_W   = (const float*)d_in[5];
    const float* gat1_as  = (const float*)d_in[6];
    const float* gat1_ad  = (const float*)d_in[7];
    const float* gat1_b   = (const float*)d_in[8];
    const float* gat2_W   = (const float*)d_in[9];
    const float* gat2_as  = (const float*)d_in[10];
    const float* gat2_ad  = (const float*)d_in[11];
    const float* gat2_b   = (const float*)d_in[12];
    const float* Wih_f    = (const float*)d_in[13];
    const float* bih_f    = (const float*)d_in[15];
    const float* bhh_f    = (const float*)d_in[16];
    const float* Wih_r    = (const float*)d_in[17];
    const float* bih_r    = (const float*)d_in[19];
    const float* bhh_r    = (const float*)d_in[20];
    const float* tab_W    = (const float*)d_in[21];
    const float* tab_b    = (const float*)d_in[22];
    const float* tab_g    = (const float*)d_in[23];
    const float* tab_bb   = (const float*)d_in[24];
    const float* fus1_W   = (const float*)d_in[25];
    const float* fus1_b   = (const float*)d_in[26];
    const float* fus_g    = (const float*)d_in[27];
    const float* fus_bb   = (const float*)d_in[28];
    const float* fus2_W   = (const float*)d_in[29];
    const float* fus2_b   = (const float*)d_in[30];
    const float* fus3_W   = (const float*)d_in[31];
    const float* fus3_b   = (const float*)d_in[32];
    float* out = (float*)d_out;

    char* ws = (char*)d_ws;
    size_t off = 0;
    auto alloc = [&](size_t bytes) -> char* {
        char* p = ws + off;
        off += (bytes + 255) & ~(size_t)255;
        return p;
    };
    float* h_lin   = (float*)alloc((size_t)N_NODES * HD * 4);
    float* h_act   = (float*)alloc((size_t)N_NODES * HD * 4);
    float* alpha_s = (float*)alloc((size_t)N_NODES * 4);
    float* alpha_d = (float*)alloc((size_t)N_NODES * 4);
    int*   deg     = (int*)alloc((size_t)N_NODES * 4);
    int*   row_ptr = (int*)alloc((size_t)(N_NODES + 1) * 4);
    int*   cursor  = (int*)alloc((size_t)N_NODES * 4);
    int*   csr_src = (int*)alloc((size_t)E_TOT * 4);
    int*   gstart  = (int*)alloc((size_t)(NB + 1) * 4);
    float* z       = (float*)alloc((size_t)NB * 320 * 4);
    float* g_f     = (float*)alloc((size_t)NB * 256 * 4);
    float* g_r     = (float*)alloc((size_t)NB * 256 * 4);
    float* tabpre  = (float*)alloc((size_t)NB * 64 * 4);
    float* z1pre   = (float*)alloc((size_t)NB * 256 * 4);
    float* z1      = (float*)alloc((size_t)NB * 256 * 4);
    float* z2      = (float*)alloc((size_t)NB * 128 * 4);

    // CSR build
    hipMemsetAsync(deg, 0, (size_t)N_NODES * 4, stream);
    count_edges<<<(E_TOT + 255) / 256, 256, 0, stream>>>(ei, deg);
    scan_kernel<<<1, 1024, 0, stream>>>(deg, row_ptr, cursor);
    fill_edges<<<(E_TOT + 255) / 256, 256, 0, stream>>>(ei, cursor, csr_src);
    graph_bounds<<<(N_NODES + 255) / 256, 256, 0, stream>>>(batch, gstart);

    int aggGrid = (N_NODES + 3) / 4;     // 4 waves per 256-thr block

    // GAT layer 1
    matmul_gat1<<<(N_NODES + 31) / 32, 256, 0, stream>>>(x, gat1_W, h_lin);
    alpha_kernel<<<aggGrid, 256, 0, stream>>>(h_lin, gat1_as, gat1_ad, alpha_s, alpha_d);
    gat_agg<<<aggGrid, 256, 0, stream>>>(h_lin, row_ptr, csr_src, alpha_s, alpha_d, gat1_b, h_act);

    // GAT layer 2
    matmul_tiled<<<dim3((N_NODES + 31) / 32, 1), 256, 0, stream>>>(h_act, gat2_W, nullptr, h_lin, N_NODES, HD, HD, 0);
    alpha_kernel<<<aggGrid, 256, 0, stream>>>(h_lin, gat2_as, gat2_ad, alpha_s, alpha_d);
    gat_agg<<<aggGrid, 256, 0, stream>>>(h_lin, row_ptr, csr_src, alpha_s, alpha_d, gat2_b, h_act);

    // mean pool -> z[:, 0:128)
    pool_kernel<<<(NB + 3) / 4, 256, 0, stream>>>(h_act, gstart, z);

    // LSTM (seq_len=1): gates = esm @ Wih^T + bih ; then nonlinearity (+bhh) -> z[:,128:256)
    matmul_tiled<<<dim3(32, 2), 256, 0, stream>>>(esm, Wih_f, bih_f, g_f, NB, ESM_DIM, 256, 0);
    matmul_tiled<<<dim3(32, 2), 256, 0, stream>>>(esm, Wih_r, bih_r, g_r, NB, ESM_DIM, 256, 0);
    lstm_gate<<<(NB * 128 + 255) / 256, 256, 0, stream>>>(g_f, g_r, bhh_f, bhh_r, z);

    // tab branch -> z[:,256:320)
    tab_pre<<<(NB * 64 + 255) / 256, 256, 0, stream>>>(tabf, tab_W, tab_b, tabpre);
    bn_relu_cols<<<64, 256, 0, stream>>>(tabpre, 64, tab_g, tab_bb, z, 320, 256);

    // fusion head
    matmul_tiled<<<dim3(32, 2), 256, 0, stream>>>(z, fus1_W, fus1_b, z1pre, NB, 320, 256, 0);
    bn_relu_cols<<<256, 256, 0, stream>>>(z1pre, 256, fus_g, fus_bb, z1, 256, 0);
    matmul_tiled<<<dim3(32, 1), 256, 0, stream>>>(z1, fus2_W, fus2_b, z2, NB, 256, 128, 1);
    final_kernel<<<(NB + 3) / 4, 256, 0, stream>>>(z2, fus3_W, fus3_b, out);

    (void)in_sizes; (void)n_in; (void)out_size; (void)ws_size;
}

// Round 2
// 730.457 us; speedup vs baseline: 1.8319x; 1.8319x over previous
//
#include <hip/hip_runtime.h>
#include <hip/hip_bf16.h>

#define N_NODES 50000
#define N_EDGES 800000
#define E_TOT   850000
#define NB      1024
#define NODE_DIM 21
#define ESM_DIM 480
#define HD      128

// ---------------- CSR build ----------------

__global__ void count_edges(const int* __restrict__ ei, int* __restrict__ deg) {
    int e = blockIdx.x * 256 + threadIdx.x;
    if (e >= E_TOT) return;
    int d = (e < N_EDGES) ? ei[N_EDGES + e] : (e - N_EDGES);
    atomicAdd(&deg[d], 1);
}

// shuffle-based single-block scan: 1024 threads, wave-scan + wave-sum scan
__global__ void scan_kernel(const int* __restrict__ deg, int* __restrict__ row_ptr,
                            int* __restrict__ cursor) {
    __shared__ int wsum[16];
    __shared__ int chunk_tot;
    int t = threadIdx.x;
    int lane = t & 63, wid = t >> 6;
    int carry = 0;
    for (int base = 0; base < N_NODES; base += 1024) {
        int i = base + t;
        int v = (i < N_NODES) ? deg[i] : 0;
        int sc = v;
#pragma unroll
        for (int off = 1; off < 64; off <<= 1) {
            int n = __shfl_up(sc, off);
            if (lane >= off) sc += n;
        }
        if (lane == 63) wsum[wid] = sc;
        __syncthreads();
        if (t < 16) {
            int x = wsum[t];
#pragma unroll
            for (int off = 1; off < 16; off <<= 1) {
                int n = __shfl_up(x, off);
                if (t >= off) x += n;
            }
            wsum[t] = x;
            if (t == 15) chunk_tot = x;
        }
        __syncthreads();
        int woff = (wid > 0) ? wsum[wid - 1] : 0;
        if (i < N_NODES) {
            int excl = carry + woff + sc - v;
            row_ptr[i] = excl;
            cursor[i] = excl;
        }
        carry += chunk_tot;
        __syncthreads();
    }
    if (t == 0) row_ptr[N_NODES] = carry;
}

__global__ void fill_edges(const int* __restrict__ ei, int* __restrict__ cursor,
                           int* __restrict__ csr_src) {
    int e = blockIdx.x * 256 + threadIdx.x;
    if (e >= E_TOT) return;
    int s, d;
    if (e < N_EDGES) { s = ei[e]; d = ei[N_EDGES + e]; }
    else             { s = d = e - N_EDGES; }
    int pos = atomicAdd(&cursor[d], 1);
    csr_src[pos] = s;
}

__global__ void graph_bounds(const int* __restrict__ batch, int* __restrict__ start) {
    int i = blockIdx.x * 256 + threadIdx.x;
    if (i >= N_NODES) return;
    int b = batch[i];
    int bp = (i == 0) ? -1 : batch[i - 1];
    for (int g = bp + 1; g <= b; ++g) start[g] = i;
    if (i == N_NODES - 1)
        for (int g = b + 1; g <= NB; ++g) start[g] = N_NODES;
}

// ---------------- GAT1 linear: [N,21]@[21x128]^T ----------------

__global__ void matmul_gat1(const float* __restrict__ X, const float* __restrict__ W,
                            float* __restrict__ out) {
    __shared__ float Xs[32][23];
    __shared__ float Ws[128][23];
    int t = threadIdx.x;
    int r0 = blockIdx.x * 32;
    for (int idx = t; idx < 128 * 21; idx += 256) Ws[idx / 21][idx % 21] = W[idx];
    for (int idx = t; idx < 32 * 21; idx += 256) {
        int r = idx / 21, k = idx % 21;
        Xs[r][k] = (r0 + r < N_NODES) ? X[(size_t)(r0 + r) * 21 + k] : 0.f;
    }
    __syncthreads();
    int f = t & 127, rsub = t >> 7;
    for (int r = rsub; r < 32; r += 2) {
        if (r0 + r >= N_NODES) break;
        float a = 0.f;
#pragma unroll
        for (int k = 0; k < 21; ++k) a += Xs[r][k] * Ws[f][k];
        out[(size_t)(r0 + r) * HD + f] = a;
    }
}

// ---------------- big tiled matmul (GAT2 linear): out[M,F] = X[M,K] @ W[F,K]^T ----------------

__global__ void matmul_tiled(const float* __restrict__ X, const float* __restrict__ W,
                             float* __restrict__ out, int M, int K, int F) {
    __shared__ float Xs[32][33];
    __shared__ float Ws[128][33];
    int t = threadIdx.x;
    int r0 = blockIdx.x * 32;
    int fb = blockIdx.y * 128;
    int f = t & 127, rsub = t >> 7;
    float acc[16];
#pragma unroll
    for (int i = 0; i < 16; ++i) acc[i] = 0.f;
    for (int kc = 0; kc < K; kc += 32) {
        int idx = t * 4;
        int xr = idx >> 5, xk = idx & 31;
        if (r0 + xr < M) {
            const float4 v = *(const float4*)&X[(size_t)(r0 + xr) * K + kc + xk];
            Xs[xr][xk] = v.x; Xs[xr][xk + 1] = v.y; Xs[xr][xk + 2] = v.z; Xs[xr][xk + 3] = v.w;
        } else {
            Xs[xr][xk] = 0.f; Xs[xr][xk + 1] = 0.f; Xs[xr][xk + 2] = 0.f; Xs[xr][xk + 3] = 0.f;
        }
#pragma unroll
        for (int i = 0; i < 16; ++i) {
            int id2 = t + 256 * i;
            int wf = id2 >> 5, wk = id2 & 31;
            Ws[wf][wk] = W[(size_t)(fb + wf) * K + kc + wk];
        }
        __syncthreads();
#pragma unroll
        for (int rr = 0; rr < 16; ++rr) {
            int r = rsub + rr * 2;
            float a = 0.f;
#pragma unroll
            for (int k = 0; k < 32; ++k) a += Xs[r][k] * Ws[f][k];
            acc[rr] += a;
        }
        __syncthreads();
    }
    for (int rr = 0; rr < 16; ++rr) {
        int r = r0 + rsub + rr * 2;
        if (r < M) out[(size_t)r * F + fb + f] = acc[rr];
    }
}

// ---------------- split-K small GEMM with atomic accumulate ----------------
// out[M,Ftot] += X[M,K] @ Wsel[F,K]^T ; tile 16 rows x 64 cols; grid.z splits K
// blockIdx.y*64 < F1 -> W1, else W2 (cols offset by F1). out must be zeroed.

__global__ void gemm_split(const float* __restrict__ X, const float* __restrict__ W1,
                           const float* __restrict__ W2, float* __restrict__ out,
                           int K, int F1, int Ftot, int Kc) {
    __shared__ float Xs[16][33];
    __shared__ float Ws[64][33];
    int t = threadIdx.x;
    int r0 = blockIdx.x * 16;
    int fb = blockIdx.y * 64;
    const float* W = (fb < F1) ? (W1 + (size_t)fb * K) : (W2 + (size_t)(fb - F1) * K);
    int k0 = blockIdx.z * Kc;
    int f = t & 63, rsub = t >> 6;
    float acc0 = 0.f, acc1 = 0.f, acc2 = 0.f, acc3 = 0.f;
    for (int kc = k0; kc < k0 + Kc; kc += 32) {
        {
            int idx = t * 2, xr = idx >> 5, xk = idx & 31;
            const float2 v = *(const float2*)&X[(size_t)(r0 + xr) * K + kc + xk];
            Xs[xr][xk] = v.x; Xs[xr][xk + 1] = v.y;
        }
        {
            int wf = t >> 2, wk = (t & 3) * 8;
            const float4* p = (const float4*)&W[(size_t)wf * K + kc + wk];
            float4 a = p[0], b = p[1];
            Ws[wf][wk] = a.x; Ws[wf][wk + 1] = a.y; Ws[wf][wk + 2] = a.z; Ws[wf][wk + 3] = a.w;
            Ws[wf][wk + 4] = b.x; Ws[wf][wk + 5] = b.y; Ws[wf][wk + 6] = b.z; Ws[wf][wk + 7] = b.w;
        }
        __syncthreads();
#pragma unroll
        for (int k = 0; k < 32; ++k) {
            float w = Ws[f][k];
            acc0 += Xs[rsub][k] * w;
            acc1 += Xs[rsub + 4][k] * w;
            acc2 += Xs[rsub + 8][k] * w;
            acc3 += Xs[rsub + 12][k] * w;
        }
        __syncthreads();
    }
    atomicAdd(&out[(size_t)(r0 + rsub) * Ftot + fb + f], acc0);
    atomicAdd(&out[(size_t)(r0 + rsub + 4) * Ftot + fb + f], acc1);
    atomicAdd(&out[(size_t)(r0 + rsub + 8) * Ftot + fb + f], acc2);
    atomicAdd(&out[(size_t)(r0 + rsub + 12) * Ftot + fb + f], acc3);
}

// ---------------- per-node alphas ----------------

__global__ void alpha_kernel(const float* __restrict__ h, const float* __restrict__ asrc,
                             const float* __restrict__ adst, float* __restrict__ alpha_s,
                             float* __restrict__ alpha_d) {
    int w = (int)((blockIdx.x * (size_t)blockDim.x + threadIdx.x) >> 6);
    int lane = threadIdx.x & 63;
    if (w >= N_NODES) return;
    float2 hv = *(const float2*)&h[(size_t)w * HD + lane * 2];
    float2 as = *(const float2*)&asrc[lane * 2];
    float2 ad = *(const float2*)&adst[lane * 2];
    float s = hv.x * as.x + hv.y * as.y;
    float d = hv.x * ad.x + hv.y * ad.y;
    for (int off = 32; off; off >>= 1) {
        s += __shfl_down(s, off);
        d += __shfl_down(d, off);
    }
    if (lane == 0) { alpha_s[w] = s; alpha_d[w] = d; }
}

// ---------------- GAT aggregation (edge softmax by dst, no atomics) ----------------

__global__ void gat_agg(const float* __restrict__ h, const int* __restrict__ row_ptr,
                        const int* __restrict__ csr_src, const float* __restrict__ alpha_s,
                        const float* __restrict__ alpha_d, const float* __restrict__ bias,
                        float* __restrict__ out) {
    int w = (int)((blockIdx.x * (size_t)blockDim.x + threadIdx.x) >> 6);
    int lane = threadIdx.x & 63;
    if (w >= N_NODES) return;
    int rs = row_ptr[w], re = row_ptr[w + 1];
    float ad = alpha_d[w];
    float m = -1e30f;
    for (int i = rs + lane; i < re; i += 64) {
        int s = csr_src[i];
        float e = alpha_s[s] + ad;
        e = (e > 0.f) ? e : 0.2f * e;
        m = fmaxf(m, e);
    }
    for (int off = 32; off; off >>= 1) m = fmaxf(m, __shfl_xor(m, off));
    float den = 0.f, ax = 0.f, ay = 0.f;
    for (int i = rs; i < re; ++i) {
        int s = csr_src[i];
        float e = alpha_s[s] + ad;
        e = (e > 0.f) ? e : 0.2f * e;
        float ex = __expf(e - m);
        den += ex;
        float2 hv = *(const float2*)&h[(size_t)s * HD + lane * 2];
        ax += ex * hv.x;
        ay += ex * hv.y;
    }
    float inv = 1.f / (den + 1e-16f);
    float2 bv = *(const float2*)&bias[lane * 2];
    float vx = fmaxf(ax * inv + bv.x, 0.f);
    float vy = fmaxf(ay * inv + bv.y, 0.f);
    *(float2*)&out[(size_t)w * HD + lane * 2] = make_float2(vx, vy);
}

// ---------------- mean pool per graph ----------------

__global__ void pool_kernel(const float* __restrict__ h, const int* __restrict__ start,
                            float* __restrict__ z) {
    int w = (int)((blockIdx.x * (size_t)blockDim.x + threadIdx.x) >> 6);
    int lane = threadIdx.x & 63;
    if (w >= NB) return;
    int s0 = start[w], s1 = start[w + 1];
    float ax = 0.f, ay = 0.f;
    for (int n = s0; n < s1; ++n) {
        float2 hv = *(const float2*)&h[(size_t)n * HD + lane * 2];
        ax += hv.x; ay += hv.y;
    }
    float c = fmaxf((float)(s1 - s0), 1.f);
    *(float2*)&z[(size_t)w * 320 + lane * 2] = make_float2(ax / c, ay / c);
}

// ---------------- LSTM nonlinearity: g[1024][512] -> z cols [128,256) ----------------

__device__ __forceinline__ float sigmoidf_(float x) { return 1.f / (1.f + __expf(-x)); }

__global__ void lstm_gate(const float* __restrict__ g,
                          const float* __restrict__ bihf, const float* __restrict__ bhhf,
                          const float* __restrict__ bihr, const float* __restrict__ bhhr,
                          float* __restrict__ z) {
    int idx = blockIdx.x * 256 + threadIdx.x;
    if (idx >= NB * 128) return;
    int b = idx >> 7, jj = idx & 127;
    int dir = jj >> 6, j = jj & 63;
    const float* gb = g + (size_t)b * 512 + dir * 256;
    const float* bi = dir ? bihr : bihf;
    const float* bh = dir ? bhhr : bhhf;
    float gi = gb[j]       + bi[j]       + bh[j];
    float gg = gb[128 + j] + bi[128 + j] + bh[128 + j];
    float go = gb[192 + j] + bi[192 + j] + bh[192 + j];
    float c = sigmoidf_(gi) * tanhf(gg);
    z[(size_t)b * 320 + 128 + jj] = sigmoidf_(go) * tanhf(c);
}

// ---------------- tab pre-BN linear ----------------

__global__ void tab_pre(const float* __restrict__ tf, const float* __restrict__ W,
                        const float* __restrict__ bias, float* __restrict__ out) {
    int idx = blockIdx.x * 256 + threadIdx.x;
    if (idx >= NB * 64) return;
    int b = idx >> 6, j = idx & 63;
    const float* x = &tf[(size_t)b * 7];
    const float* w = &W[(size_t)j * 7];
    float a = bias[j];
#pragma unroll
    for (int k = 0; k < 7; ++k) a += x[k] * w[k];
    out[idx] = a;
}

// ---------------- BatchNorm (training stats) + relu, one block per column ----------------

__global__ void bn_relu_cols(const float* __restrict__ in, int cols,
                             const float* __restrict__ g, const float* __restrict__ b,
                             float* __restrict__ out, int out_stride, int out_col0) {
    int j = blockIdx.x;
    int t = threadIdx.x;
    __shared__ float ssum[256], ssq[256];
    float vals[4];
    float s = 0.f, q = 0.f;
#pragma unroll
    for (int i = 0; i < 4; ++i) {
        float v = in[(size_t)(t + 256 * i) * cols + j];
        vals[i] = v; s += v; q += v * v;
    }
    ssum[t] = s; ssq[t] = q;
    __syncthreads();
    for (int off = 128; off; off >>= 1) {
        if (t < off) { ssum[t] += ssum[t + off]; ssq[t] += ssq[t + off]; }
        __syncthreads();
    }
    float mu = ssum[0] * (1.f / 1024.f);
    float var = ssq[0] * (1.f / 1024.f) - mu * mu;
    float sc = rsqrtf(var + 1e-5f) * g[j];
    float bb = b[j] - mu * sc;
#pragma unroll
    for (int i = 0; i < 4; ++i) {
        float v = vals[i] * sc + bb;
        out[(size_t)(t + 256 * i) * out_stride + out_col0 + j] = fmaxf(v, 0.f);
    }
}

// ---------------- final: relu(z2 + b2) @ fus3_W^T + fus3_b ----------------

__global__ void final_kernel(const float* __restrict__ z2, const float* __restrict__ b2,
                             const float* __restrict__ W, const float* __restrict__ b,
                             float* __restrict__ out) {
    int w = (int)((blockIdx.x * (size_t)blockDim.x + threadIdx.x) >> 6);
    int lane = threadIdx.x & 63;
    if (w >= NB) return;
    float2 zv = *(const float2*)&z2[(size_t)w * 128 + lane * 2];
    float2 bv = *(const float2*)&b2[lane * 2];
    float2 wv = *(const float2*)&W[lane * 2];
    float zx = fmaxf(zv.x + bv.x, 0.f);
    float zy = fmaxf(zv.y + bv.y, 0.f);
    float s = zx * wv.x + zy * wv.y;
    for (int off = 32; off; off >>= 1) s += __shfl_down(s, off);
    if (lane == 0) out[w] = s + b[0];
}

// ---------------- launch ----------------

extern "C" void kernel_launch(void* const* d_in, const int* in_sizes, int n_in,
                              void* d_out, int out_size, void* d_ws, size_t ws_size,
                              hipStream_t stream) {
    const float* x        = (const float*)d_in[0];
    const int*   ei       = (const int*)d_in[1];
    const int*   batch    = (const int*)d_in[2];
    const float* esm      = (const float*)d_in[3];
    const float* tabf     = (const float*)d_in[4];
    const float* gat1_W   = (const float*)d_in[5];
    const float* gat1_as  = (const float*)d_in[6];
    const float* gat1_ad  = (const float*)d_in[7];
    const float* gat1_b   = (const float*)d_in[8];
    const float* gat2_W   = (const float*)d_in[9];
    const float* gat2_as  = (const float*)d_in[10];
    const float* gat2_ad  = (const float*)d_in[11];
    const float* gat2_b   = (const float*)d_in[12];
    const float* Wih_f    = (const float*)d_in[13];
    const float* bih_f    = (const float*)d_in[15];
    const float* bhh_f    = (const float*)d_in[16];
    const float* Wih_r    = (const float*)d_in[17];
    const float* bih_r    = (const float*)d_in[19];
    const float* bhh_r    = (const float*)d_in[20];
    const float* tab_W    = (const float*)d_in[21];
    const float* tab_b    = (const float*)d_in[22];
    const float* tab_g    = (const float*)d_in[23];
    const float* tab_bb   = (const float*)d_in[24];
    const float* fus1_W   = (const float*)d_in[25];
    const float* fus_g    = (const float*)d_in[27];
    const float* fus_bb   = (const float*)d_in[28];
    const float* fus2_W   = (const float*)d_in[29];
    const float* fus2_b   = (const float*)d_in[30];
    const float* fus3_W   = (const float*)d_in[31];
    const float* fus3_b   = (const float*)d_in[32];
    float* out = (float*)d_out;

    char* ws = (char*)d_ws;
    size_t off = 0;
    auto alloc = [&](size_t bytes) -> char* {
        char* p = ws + off;
        off += (bytes + 255) & ~(size_t)255;
        return p;
    };
    float* h_lin   = (float*)alloc((size_t)N_NODES * HD * 4);
    float* h_act   = (float*)alloc((size_t)N_NODES * HD * 4);
    float* alpha_s = (float*)alloc((size_t)N_NODES * 4);
    float* alpha_d = (float*)alloc((size_t)N_NODES * 4);
    int*   deg     = (int*)alloc((size_t)N_NODES * 4);
    int*   row_ptr = (int*)alloc((size_t)(N_NODES + 1) * 4);
    int*   cursor  = (int*)alloc((size_t)N_NODES * 4);
    int*   csr_src = (int*)alloc((size_t)E_TOT * 4);
    int*   gstart  = (int*)alloc((size_t)(NB + 1) * 4);
    float* z       = (float*)alloc((size_t)NB * 320 * 4);
    float* g_lstm  = (float*)alloc((size_t)NB * 512 * 4);
    float* tabpre  = (float*)alloc((size_t)NB * 64 * 4);
    float* z1pre   = (float*)alloc((size_t)NB * 256 * 4);
    float* z1      = (float*)alloc((size_t)NB * 256 * 4);
    float* z2      = (float*)alloc((size_t)NB * 128 * 4);

    // CSR build
    hipMemsetAsync(deg, 0, (size_t)N_NODES * 4, stream);
    count_edges<<<(E_TOT + 255) / 256, 256, 0, stream>>>(ei, deg);
    scan_kernel<<<1, 1024, 0, stream>>>(deg, row_ptr, cursor);
    fill_edges<<<(E_TOT + 255) / 256, 256, 0, stream>>>(ei, cursor, csr_src);
    graph_bounds<<<(N_NODES + 255) / 256, 256, 0, stream>>>(batch, gstart);

    // zero accumulation buffers for split-K GEMMs
    hipMemsetAsync(g_lstm, 0, (size_t)NB * 512 * 4, stream);
    hipMemsetAsync(z1pre, 0, (size_t)NB * 256 * 4, stream);
    hipMemsetAsync(z2, 0, (size_t)NB * 128 * 4, stream);

    int aggGrid = (N_NODES + 3) / 4;

    // GAT layer 1
    matmul_gat1<<<(N_NODES + 31) / 32, 256, 0, stream>>>(x, gat1_W, h_lin);
    alpha_kernel<<<aggGrid, 256, 0, stream>>>(h_lin, gat1_as, gat1_ad, alpha_s, alpha_d);
    gat_agg<<<aggGrid, 256, 0, stream>>>(h_lin, row_ptr, csr_src, alpha_s, alpha_d, gat1_b, h_act);

    // GAT layer 2
    matmul_tiled<<<dim3((N_NODES + 31) / 32, 1), 256, 0, stream>>>(h_act, gat2_W, h_lin, N_NODES, HD, HD);
    alpha_kernel<<<aggGrid, 256, 0, stream>>>(h_lin, gat2_as, gat2_ad, alpha_s, alpha_d);
    gat_agg<<<aggGrid, 256, 0, stream>>>(h_lin, row_ptr, csr_src, alpha_s, alpha_d, gat2_b, h_act);

    // mean pool -> z[:, 0:128)
    pool_kernel<<<(NB + 3) / 4, 256, 0, stream>>>(h_act, gstart, z);

    // LSTM gates (f+r fused): g_lstm[1024,512] = esm @ [Wih_f;Wih_r]^T (no bias)
    gemm_split<<<dim3(64, 8, 3), 256, 0, stream>>>(esm, Wih_f, Wih_r, g_lstm, ESM_DIM, 256, 512, 160);
    lstm_gate<<<(NB * 128 + 255) / 256, 256, 0, stream>>>(g_lstm, bih_f, bhh_f, bih_r, bhh_r, z);

    // tab branch -> z[:,256:320)
    tab_pre<<<(NB * 64 + 255) / 256, 256, 0, stream>>>(tabf, tab_W, tab_b, tabpre);
    bn_relu_cols<<<64, 256, 0, stream>>>(tabpre, 64, tab_g, tab_bb, z, 320, 256);

    // fusion head (fus1 bias cancels in BN; fus2 bias+relu folded into final)
    gemm_split<<<dim3(64, 4, 2), 256, 0, stream>>>(z, fus1_W, nullptr, z1pre, 320, 256, 256, 160);
    bn_relu_cols<<<256, 256, 0, stream>>>(z1pre, 256, fus_g, fus_bb, z1, 256, 0);
    gemm_split<<<dim3(64, 2, 2), 256, 0, stream>>>(z1, fus2_W, nullptr, z2, 256, 128, 128, 128);
    final_kernel<<<(NB + 3) / 4, 256, 0, stream>>>(z2, fus2_b, fus3_W, fus3_b, out);

    (void)in_sizes; (void)n_in; (void)out_size; (void)ws_size;
}

// Round 3
// 589.364 us; speedup vs baseline: 2.2705x; 1.2394x over previous
//
#include <hip/hip_runtime.h>
#include <hip/hip_bf16.h>

#define N_NODES 50000
#define N_PAD   50048
#define N_EDGES 800000
#define E_TOT   850000
#define NB      1024
#define ESM_DIM 480
#define HD      128

typedef short short8 __attribute__((ext_vector_type(8)));
typedef float f32x4 __attribute__((ext_vector_type(4)));

__device__ __forceinline__ float bf2f(unsigned int u) {
    union { unsigned int i; float f; } c; c.i = u << 16; return c.f;
}
__device__ __forceinline__ unsigned short f2bf(float f) {
    union { float f; unsigned int i; } c; c.f = f;
    unsigned int i = c.i;
    return (unsigned short)((i + 0x7FFFu + ((i >> 16) & 1u)) >> 16);
}

// ---------------- CSR build ----------------

__global__ void count_edges(const int* __restrict__ ei, int* __restrict__ deg) {
    int e = blockIdx.x * 256 + threadIdx.x;
    if (e >= E_TOT) return;
    int d = (e < N_EDGES) ? ei[N_EDGES + e] : (e - N_EDGES);
    atomicAdd(&deg[d], 1);
}

__global__ void scan_kernel(const int* __restrict__ deg, int* __restrict__ row_ptr,
                            int* __restrict__ cursor) {
    __shared__ int wsum[16];
    __shared__ int chunk_tot;
    int t = threadIdx.x;
    int lane = t & 63, wid = t >> 6;
    int carry = 0;
    for (int base = 0; base < N_NODES; base += 1024) {
        int i = base + t;
        int v = (i < N_NODES) ? deg[i] : 0;
        int sc = v;
#pragma unroll
        for (int off = 1; off < 64; off <<= 1) {
            int n = __shfl_up(sc, off);
            if (lane >= off) sc += n;
        }
        if (lane == 63) wsum[wid] = sc;
        __syncthreads();
        if (t < 16) {
            int x = wsum[t];
#pragma unroll
            for (int off = 1; off < 16; off <<= 1) {
                int n = __shfl_up(x, off);
                if (t >= off) x += n;
            }
            wsum[t] = x;
            if (t == 15) chunk_tot = x;
        }
        __syncthreads();
        int woff = (wid > 0) ? wsum[wid - 1] : 0;
        if (i < N_NODES) {
            int excl = carry + woff + sc - v;
            row_ptr[i] = excl;
            cursor[i] = excl;
        }
        carry += chunk_tot;
        __syncthreads();
    }
    if (t == 0) row_ptr[N_NODES] = carry;
}

__global__ void fill_edges(const int* __restrict__ ei, int* __restrict__ cursor,
                           int* __restrict__ csr_src) {
    int e = blockIdx.x * 256 + threadIdx.x;
    if (e >= E_TOT) return;
    int s, d;
    if (e < N_EDGES) { s = ei[e]; d = ei[N_EDGES + e]; }
    else             { s = d = e - N_EDGES; }
    int pos = atomicAdd(&cursor[d], 1);
    csr_src[pos] = s;
}

__global__ void graph_bounds(const int* __restrict__ batch, int* __restrict__ start) {
    int i = blockIdx.x * 256 + threadIdx.x;
    if (i >= N_NODES) return;
    int b = batch[i];
    int bp = (i == 0) ? -1 : batch[i - 1];
    for (int g = bp + 1; g <= b; ++g) start[g] = i;
    if (i == N_NODES - 1)
        for (int g = b + 1; g <= NB; ++g) start[g] = N_NODES;
}

// ---------------- GAT1 linear: [N,21]@[21x128]^T -> bf16 out ----------------

__global__ void matmul_gat1(const float* __restrict__ X, const float* __restrict__ W,
                            unsigned short* __restrict__ out) {
    __shared__ float Xs[32][23];
    __shared__ float Ws[128][23];
    int t = threadIdx.x;
    int r0 = blockIdx.x * 32;
    for (int idx = t; idx < 128 * 21; idx += 256) Ws[idx / 21][idx % 21] = W[idx];
    for (int idx = t; idx < 32 * 21; idx += 256) {
        int r = idx / 21, k = idx % 21;
        Xs[r][k] = (r0 + r < N_NODES) ? X[(size_t)(r0 + r) * 21 + k] : 0.f;
    }
    __syncthreads();
    int f = t & 127, rsub = t >> 7;
    for (int r = rsub; r < 32; r += 2) {
        if (r0 + r >= N_NODES) break;
        float a = 0.f;
#pragma unroll
        for (int k = 0; k < 21; ++k) a += Xs[r][k] * Ws[f][k];
        out[(size_t)(r0 + r) * HD + f] = f2bf(a);
    }
}

// ---------------- GAT2 linear: MFMA bf16, C = A[N,128] @ W[128,128]^T ----------------
// block = 256 thr = 4 waves; wave handles 16 rows x 128 cols; W staged to LDS (bf16, +8 pad)

__global__ __launch_bounds__(256) void gemm_mfma(const unsigned short* __restrict__ A,
                                                 const float* __restrict__ W,
                                                 unsigned short* __restrict__ out, int M) {
    __shared__ unsigned short Wlds[128 * 136];
    int t = threadIdx.x;
    {
        int row = t >> 1, half = t & 1;
        const float4* src = (const float4*)&W[row * 128 + half * 64];
#pragma unroll
        for (int i = 0; i < 16; ++i) {
            float4 v = src[i];
            ushort4 u = make_ushort4(f2bf(v.x), f2bf(v.y), f2bf(v.z), f2bf(v.w));
            *(ushort4*)&Wlds[row * 136 + half * 64 + i * 4] = u;
        }
    }
    __syncthreads();
    int wid = t >> 6, L = t & 63;
    int quad = L >> 4, lo = L & 15;
    int m0 = blockIdx.x * 64 + wid * 16;
    short8 afrag[4];
#pragma unroll
    for (int ch = 0; ch < 4; ++ch)
        afrag[ch] = *(const short8*)&A[(size_t)(m0 + lo) * HD + ch * 32 + quad * 8];
#pragma unroll
    for (int ft = 0; ft < 8; ++ft) {
        f32x4 acc = {0.f, 0.f, 0.f, 0.f};
#pragma unroll
        for (int ch = 0; ch < 4; ++ch) {
            short8 b = *(const short8*)&Wlds[(ft * 16 + lo) * 136 + ch * 32 + quad * 8];
            acc = __builtin_amdgcn_mfma_f32_16x16x32_bf16(afrag[ch], b, acc, 0, 0, 0);
        }
#pragma unroll
        for (int r = 0; r < 4; ++r) {
            int m = m0 + quad * 4 + r;
            if (m < M) out[(size_t)m * HD + ft * 16 + lo] = f2bf(acc[r]);
        }
    }
}

// ---------------- per-node alphas (bf16 h) ----------------

__global__ void alpha_kernel(const unsigned short* __restrict__ h, const float* __restrict__ asrc,
                             const float* __restrict__ adst, float* __restrict__ alpha_s,
                             float* __restrict__ alpha_d) {
    int w = (int)((blockIdx.x * (size_t)blockDim.x + threadIdx.x) >> 6);
    int lane = threadIdx.x & 63;
    if (w >= N_NODES) return;
    unsigned int hv = *(const unsigned int*)&h[(size_t)w * HD + lane * 2];
    float hx = bf2f(hv & 0xFFFFu), hy = bf2f(hv >> 16);
    float2 as = *(const float2*)&asrc[lane * 2];
    float2 ad = *(const float2*)&adst[lane * 2];
    float s = hx * as.x + hy * as.y;
    float d = hx * ad.x + hy * ad.y;
    for (int off = 32; off; off >>= 1) {
        s += __shfl_down(s, off);
        d += __shfl_down(d, off);
    }
    if (lane == 0) { alpha_s[w] = s; alpha_d[w] = d; }
}

// ---------------- GAT aggregation (bf16 gathers; out bf16 or fp32) ----------------

template <int BF_OUT>
__global__ void gat_agg(const unsigned short* __restrict__ h, const int* __restrict__ row_ptr,
                        const int* __restrict__ csr_src, const float* __restrict__ alpha_s,
                        const float* __restrict__ alpha_d, const float* __restrict__ bias,
                        void* __restrict__ outp) {
    int w = (int)((blockIdx.x * (size_t)blockDim.x + threadIdx.x) >> 6);
    int lane = threadIdx.x & 63;
    if (w >= N_NODES) return;
    int rs = row_ptr[w], re = row_ptr[w + 1];
    float ad = alpha_d[w];
    float m = -1e30f;
    for (int i = rs + lane; i < re; i += 64) {
        int s = csr_src[i];
        float e = alpha_s[s] + ad;
        e = (e > 0.f) ? e : 0.2f * e;
        m = fmaxf(m, e);
    }
    for (int off = 32; off; off >>= 1) m = fmaxf(m, __shfl_xor(m, off));
    float den = 0.f, ax = 0.f, ay = 0.f;
    for (int i = rs; i < re; ++i) {
        int s = csr_src[i];
        float e = alpha_s[s] + ad;
        e = (e > 0.f) ? e : 0.2f * e;
        float ex = __expf(e - m);
        den += ex;
        unsigned int hv = *(const unsigned int*)&h[(size_t)s * HD + lane * 2];
        ax += ex * bf2f(hv & 0xFFFFu);
        ay += ex * bf2f(hv >> 16);
    }
    float inv = 1.f / (den + 1e-16f);
    float2 bv = *(const float2*)&bias[lane * 2];
    float vx = fmaxf(ax * inv + bv.x, 0.f);
    float vy = fmaxf(ay * inv + bv.y, 0.f);
    if (BF_OUT) {
        unsigned short* o = (unsigned short*)outp;
        unsigned int pv = (unsigned int)f2bf(vx) | ((unsigned int)f2bf(vy) << 16);
        *(unsigned int*)&o[(size_t)w * HD + lane * 2] = pv;
    } else {
        float* o = (float*)outp;
        *(float2*)&o[(size_t)w * HD + lane * 2] = make_float2(vx, vy);
    }
}

// ---------------- mean pool per graph ----------------

__global__ void pool_kernel(const float* __restrict__ h, const int* __restrict__ start,
                            float* __restrict__ z) {
    int w = (int)((blockIdx.x * (size_t)blockDim.x + threadIdx.x) >> 6);
    int lane = threadIdx.x & 63;
    if (w >= NB) return;
    int s0 = start[w], s1 = start[w + 1];
    float ax = 0.f, ay = 0.f;
    for (int n = s0; n < s1; ++n) {
        float2 hv = *(const float2*)&h[(size_t)n * HD + lane * 2];
        ax += hv.x; ay += hv.y;
    }
    float c = fmaxf((float)(s1 - s0), 1.f);
    *(float2*)&z[(size_t)w * 320 + lane * 2] = make_float2(ax / c, ay / c);
}

// ---------------- split-K small GEMM with atomic accumulate ----------------

__global__ void gemm_split(const float* __restrict__ X, const float* __restrict__ W1,
                           const float* __restrict__ W2, float* __restrict__ out,
                           int K, int F1, int Ftot, int Kc) {
    __shared__ float Xs[16][33];
    __shared__ float Ws[64][33];
    int t = threadIdx.x;
    int r0 = blockIdx.x * 16;
    int fb = blockIdx.y * 64;
    const float* W = (fb < F1) ? (W1 + (size_t)fb * K) : (W2 + (size_t)(fb - F1) * K);
    int k0 = blockIdx.z * Kc;
    int f = t & 63, rsub = t >> 6;
    float acc0 = 0.f, acc1 = 0.f, acc2 = 0.f, acc3 = 0.f;
    for (int kc = k0; kc < k0 + Kc; kc += 32) {
        {
            int idx = t * 2, xr = idx >> 5, xk = idx & 31;
            const float2 v = *(const float2*)&X[(size_t)(r0 + xr) * K + kc + xk];
            Xs[xr][xk] = v.x; Xs[xr][xk + 1] = v.y;
        }
        {
            int wf = t >> 2, wk = (t & 3) * 8;
            const float4* p = (const float4*)&W[(size_t)wf * K + kc + wk];
            float4 a = p[0], b = p[1];
            Ws[wf][wk] = a.x; Ws[wf][wk + 1] = a.y; Ws[wf][wk + 2] = a.z; Ws[wf][wk + 3] = a.w;
            Ws[wf][wk + 4] = b.x; Ws[wf][wk + 5] = b.y; Ws[wf][wk + 6] = b.z; Ws[wf][wk + 7] = b.w;
        }
        __syncthreads();
#pragma unroll
        for (int k = 0; k < 32; ++k) {
            float w = Ws[f][k];
            acc0 += Xs[rsub][k] * w;
            acc1 += Xs[rsub + 4][k] * w;
            acc2 += Xs[rsub + 8][k] * w;
            acc3 += Xs[rsub + 12][k] * w;
        }
        __syncthreads();
    }
    atomicAdd(&out[(size_t)(r0 + rsub) * Ftot + fb + f], acc0);
    atomicAdd(&out[(size_t)(r0 + rsub + 4) * Ftot + fb + f], acc1);
    atomicAdd(&out[(size_t)(r0 + rsub + 8) * Ftot + fb + f], acc2);
    atomicAdd(&out[(size_t)(r0 + rsub + 12) * Ftot + fb + f], acc3);
}

// ---------------- LSTM nonlinearity ----------------

__device__ __forceinline__ float sigmoidf_(float x) { return 1.f / (1.f + __expf(-x)); }

__global__ void lstm_gate(const float* __restrict__ g,
                          const float* __restrict__ bihf, const float* __restrict__ bhhf,
                          const float* __restrict__ bihr, const float* __restrict__ bhhr,
                          float* __restrict__ z) {
    int idx = blockIdx.x * 256 + threadIdx.x;
    if (idx >= NB * 128) return;
    int b = idx >> 7, jj = idx & 127;
    int dir = jj >> 6, j = jj & 63;
    const float* gb = g + (size_t)b * 512 + dir * 256;
    const float* bi = dir ? bihr : bihf;
    const float* bh = dir ? bhhr : bhhf;
    float gi = gb[j]       + bi[j]       + bh[j];
    float gg = gb[128 + j] + bi[128 + j] + bh[128 + j];
    float go = gb[192 + j] + bi[192 + j] + bh[192 + j];
    float c = sigmoidf_(gi) * tanhf(gg);
    z[(size_t)b * 320 + 128 + jj] = sigmoidf_(go) * tanhf(c);
}

// ---------------- tab pre-BN linear ----------------

__global__ void tab_pre(const float* __restrict__ tf, const float* __restrict__ W,
                        const float* __restrict__ bias, float* __restrict__ out) {
    int idx = blockIdx.x * 256 + threadIdx.x;
    if (idx >= NB * 64) return;
    int b = idx >> 6, j = idx & 63;
    const float* x = &tf[(size_t)b * 7];
    const float* w = &W[(size_t)j * 7];
    float a = bias[j];
#pragma unroll
    for (int k = 0; k < 7; ++k) a += x[k] * w[k];
    out[idx] = a;
}

// ---------------- BatchNorm (training stats) + relu ----------------

__global__ void bn_relu_cols(const float* __restrict__ in, int cols,
                             const float* __restrict__ g, const float* __restrict__ b,
                             float* __restrict__ out, int out_stride, int out_col0) {
    int j = blockIdx.x;
    int t = threadIdx.x;
    __shared__ float ssum[256], ssq[256];
    float vals[4];
    float s = 0.f, q = 0.f;
#pragma unroll
    for (int i = 0; i < 4; ++i) {
        float v = in[(size_t)(t + 256 * i) * cols + j];
        vals[i] = v; s += v; q += v * v;
    }
    ssum[t] = s; ssq[t] = q;
    __syncthreads();
    for (int off = 128; off; off >>= 1) {
        if (t < off) { ssum[t] += ssum[t + off]; ssq[t] += ssq[t + off]; }
        __syncthreads();
    }
    float mu = ssum[0] * (1.f / 1024.f);
    float var = ssq[0] * (1.f / 1024.f) - mu * mu;
    float sc = rsqrtf(var + 1e-5f) * g[j];
    float bb = b[j] - mu * sc;
#pragma unroll
    for (int i = 0; i < 4; ++i) {
        float v = vals[i] * sc + bb;
        out[(size_t)(t + 256 * i) * out_stride + out_col0 + j] = fmaxf(v, 0.f);
    }
}

// ---------------- final: relu(z2 + b2) @ fus3_W^T + fus3_b ----------------

__global__ void final_kernel(const float* __restrict__ z2, const float* __restrict__ b2,
                             const float* __restrict__ W, const float* __restrict__ b,
                             float* __restrict__ out) {
    int w = (int)((blockIdx.x * (size_t)blockDim.x + threadIdx.x) >> 6);
    int lane = threadIdx.x & 63;
    if (w >= NB) return;
    float2 zv = *(const float2*)&z2[(size_t)w * 128 + lane * 2];
    float2 bv = *(const float2*)&b2[lane * 2];
    float2 wv = *(const float2*)&W[lane * 2];
    float zx = fmaxf(zv.x + bv.x, 0.f);
    float zy = fmaxf(zv.y + bv.y, 0.f);
    float s = zx * wv.x + zy * wv.y;
    for (int off = 32; off; off >>= 1) s += __shfl_down(s, off);
    if (lane == 0) out[w] = s + b[0];
}

// ---------------- launch ----------------

extern "C" void kernel_launch(void* const* d_in, const int* in_sizes, int n_in,
                              void* d_out, int out_size, void* d_ws, size_t ws_size,
                              hipStream_t stream) {
    const float* x        = (const float*)d_in[0];
    const int*   ei       = (const int*)d_in[1];
    const int*   batch    = (const int*)d_in[2];
    const float* esm      = (const float*)d_in[3];
    const float* tabf     = (const float*)d_in[4];
    const float* gat1_W   = (const float*)d_in[5];
    const float* gat1_as  = (const float*)d_in[6];
    const float* gat1_ad  = (const float*)d_in[7];
    const float* gat1_b   = (const float*)d_in[8];
    const float* gat2_W   = (const float*)d_in[9];
    const float* gat2_as  = (const float*)d_in[10];
    const float* gat2_ad  = (const float*)d_in[11];
    const float* gat2_b   = (const float*)d_in[12];
    const float* Wih_f    = (const float*)d_in[13];
    const float* bih_f    = (const float*)d_in[15];
    const float* bhh_f    = (const float*)d_in[16];
    const float* Wih_r    = (const float*)d_in[17];
    const float* bih_r    = (const float*)d_in[19];
    const float* bhh_r    = (const float*)d_in[20];
    const float* tab_W    = (const float*)d_in[21];
    const float* tab_b    = (const float*)d_in[22];
    const float* tab_g    = (const float*)d_in[23];
    const float* tab_bb   = (const float*)d_in[24];
    const float* fus1_W   = (const float*)d_in[25];
    const float* fus_g    = (const float*)d_in[27];
    const float* fus_bb   = (const float*)d_in[28];
    const float* fus2_W   = (const float*)d_in[29];
    const float* fus2_b   = (const float*)d_in[30];
    const float* fus3_W   = (const float*)d_in[31];
    const float* fus3_b   = (const float*)d_in[32];
    float* out = (float*)d_out;

    char* ws = (char*)d_ws;
    size_t off = 0;
    auto alloc = [&](size_t bytes) -> char* {
        char* p = ws + off;
        off += (bytes + 255) & ~(size_t)255;
        return p;
    };
    unsigned short* h0_bf = (unsigned short*)alloc((size_t)N_PAD * HD * 2);  // gat1 linear out
    unsigned short* hA_bf = (unsigned short*)alloc((size_t)N_PAD * HD * 2);  // layer1 agg out (GEMM A)
    unsigned short* h2_bf = (unsigned short*)alloc((size_t)N_PAD * HD * 2);  // GEMM out
    float* h_act   = (float*)alloc((size_t)N_NODES * HD * 4);                // layer2 agg out
    float* alpha_s = (float*)alloc((size_t)N_NODES * 4);
    float* alpha_d = (float*)alloc((size_t)N_NODES * 4);
    int*   deg     = (int*)alloc((size_t)N_NODES * 4);
    int*   row_ptr = (int*)alloc((size_t)(N_NODES + 1) * 4);
    int*   cursor  = (int*)alloc((size_t)N_NODES * 4);
    int*   csr_src = (int*)alloc((size_t)E_TOT * 4);
    int*   gstart  = (int*)alloc((size_t)(NB + 1) * 4);
    float* z       = (float*)alloc((size_t)NB * 320 * 4);
    float* g_lstm  = (float*)alloc((size_t)NB * 512 * 4);
    float* tabpre  = (float*)alloc((size_t)NB * 64 * 4);
    float* z1pre   = (float*)alloc((size_t)NB * 256 * 4);
    float* z1      = (float*)alloc((size_t)NB * 256 * 4);
    float* z2      = (float*)alloc((size_t)NB * 128 * 4);

    // CSR build
    hipMemsetAsync(deg, 0, (size_t)N_NODES * 4, stream);
    count_edges<<<(E_TOT + 255) / 256, 256, 0, stream>>>(ei, deg);
    scan_kernel<<<1, 1024, 0, stream>>>(deg, row_ptr, cursor);
    fill_edges<<<(E_TOT + 255) / 256, 256, 0, stream>>>(ei, cursor, csr_src);
    graph_bounds<<<(N_NODES + 255) / 256, 256, 0, stream>>>(batch, gstart);

    // zero accumulation buffers for split-K GEMMs
    hipMemsetAsync(g_lstm, 0, (size_t)NB * 512 * 4, stream);
    hipMemsetAsync(z1pre, 0, (size_t)NB * 256 * 4, stream);
    hipMemsetAsync(z2, 0, (size_t)NB * 128 * 4, stream);

    int aggGrid = (N_NODES + 3) / 4;

    // GAT layer 1
    matmul_gat1<<<(N_NODES + 31) / 32, 256, 0, stream>>>(x, gat1_W, h0_bf);
    alpha_kernel<<<aggGrid, 256, 0, stream>>>(h0_bf, gat1_as, gat1_ad, alpha_s, alpha_d);
    gat_agg<1><<<aggGrid, 256, 0, stream>>>(h0_bf, row_ptr, csr_src, alpha_s, alpha_d, gat1_b, hA_bf);

    // GAT layer 2
    gemm_mfma<<<N_PAD / 64, 256, 0, stream>>>(hA_bf, gat2_W, h2_bf, N_NODES);
    alpha_kernel<<<aggGrid, 256, 0, stream>>>(h2_bf, gat2_as, gat2_ad, alpha_s, alpha_d);
    gat_agg<0><<<aggGrid, 256, 0, stream>>>(h2_bf, row_ptr, csr_src, alpha_s, alpha_d, gat2_b, h_act);

    // mean pool -> z[:, 0:128)
    pool_kernel<<<(NB + 3) / 4, 256, 0, stream>>>(h_act, gstart, z);

    // LSTM gates (f+r fused)
    gemm_split<<<dim3(64, 8, 3), 256, 0, stream>>>(esm, Wih_f, Wih_r, g_lstm, ESM_DIM, 256, 512, 160);
    lstm_gate<<<(NB * 128 + 255) / 256, 256, 0, stream>>>(g_lstm, bih_f, bhh_f, bih_r, bhh_r, z);

    // tab branch
    tab_pre<<<(NB * 64 + 255) / 256, 256, 0, stream>>>(tabf, tab_W, tab_b, tabpre);
    bn_relu_cols<<<64, 256, 0, stream>>>(tabpre, 64, tab_g, tab_bb, z, 320, 256);

    // fusion head
    gemm_split<<<dim3(64, 4, 2), 256, 0, stream>>>(z, fus1_W, nullptr, z1pre, 320, 256, 256, 160);
    bn_relu_cols<<<256, 256, 0, stream>>>(z1pre, 256, fus_g, fus_bb, z1, 256, 0);
    gemm_split<<<dim3(64, 2, 2), 256, 0, stream>>>(z1, fus2_W, nullptr, z2, 256, 128, 128, 128);
    final_kernel<<<(NB + 3) / 4, 256, 0, stream>>>(z2, fus2_b, fus3_W, fus3_b, out);

    (void)in_sizes; (void)n_in; (void)out_size; (void)ws_size;
}

// Round 4
// 468.111 us; speedup vs baseline: 2.8586x; 1.2590x over previous
//
#include <hip/hip_runtime.h>
#include <hip/hip_bf16.h>

#define N_NODES 50000
#define N_PAD   50048
#define N_EDGES 800000
#define E_TOT   850000
#define NB      1024
#define ESM_DIM 480
#define HD      128

typedef short short8 __attribute__((ext_vector_type(8)));
typedef unsigned short ushort8 __attribute__((ext_vector_type(8)));
typedef float f32x4 __attribute__((ext_vector_type(4)));

__device__ __forceinline__ float bf2f(unsigned int u) {
    union { unsigned int i; float f; } c; c.i = u << 16; return c.f;
}
__device__ __forceinline__ unsigned short f2bf(float f) {
    union { float f; unsigned int i; } c; c.f = f;
    unsigned int i = c.i;
    return (unsigned short)((i + 0x7FFFu + ((i >> 16) & 1u)) >> 16);
}

// ---------------- CSR build ----------------

__global__ void count_edges(const int* __restrict__ ei, int* __restrict__ deg) {
    int e = blockIdx.x * 256 + threadIdx.x;
    if (e >= E_TOT) return;
    int d = (e < N_EDGES) ? ei[N_EDGES + e] : (e - N_EDGES);
    atomicAdd(&deg[d], 1);
}

__global__ void scan_kernel(const int* __restrict__ deg, int* __restrict__ row_ptr,
                            int* __restrict__ cursor) {
    __shared__ int wsum[16];
    __shared__ int chunk_tot;
    int t = threadIdx.x;
    int lane = t & 63, wid = t >> 6;
    int carry = 0;
    for (int base = 0; base < N_NODES; base += 1024) {
        int i = base + t;
        int v = (i < N_NODES) ? deg[i] : 0;
        int sc = v;
#pragma unroll
        for (int off = 1; off < 64; off <<= 1) {
            int n = __shfl_up(sc, off);
            if (lane >= off) sc += n;
        }
        if (lane == 63) wsum[wid] = sc;
        __syncthreads();
        if (t < 16) {
            int x = wsum[t];
#pragma unroll
            for (int off = 1; off < 16; off <<= 1) {
                int n = __shfl_up(x, off);
                if (t >= off) x += n;
            }
            wsum[t] = x;
            if (t == 15) chunk_tot = x;
        }
        __syncthreads();
        int woff = (wid > 0) ? wsum[wid - 1] : 0;
        if (i < N_NODES) {
            int excl = carry + woff + sc - v;
            row_ptr[i] = excl;
            cursor[i] = excl;
        }
        carry += chunk_tot;
        __syncthreads();
    }
    if (t == 0) row_ptr[N_NODES] = carry;
}

__global__ void fill_edges(const int* __restrict__ ei, int* __restrict__ cursor,
                           int* __restrict__ csr_src) {
    int e = blockIdx.x * 256 + threadIdx.x;
    if (e >= E_TOT) return;
    int s, d;
    if (e < N_EDGES) { s = ei[e]; d = ei[N_EDGES + e]; }
    else             { s = d = e - N_EDGES; }
    int pos = atomicAdd(&cursor[d], 1);
    csr_src[pos] = s;
}

__global__ void graph_bounds(const int* __restrict__ batch, int* __restrict__ start) {
    int i = blockIdx.x * 256 + threadIdx.x;
    if (i >= N_NODES) return;
    int b = batch[i];
    int bp = (i == 0) ? -1 : batch[i - 1];
    for (int g = bp + 1; g <= b; ++g) start[g] = i;
    if (i == N_NODES - 1)
        for (int g = b + 1; g <= NB; ++g) start[g] = N_NODES;
}

// ---------------- GAT1 linear: [N,21]@[21x128]^T -> bf16 out ----------------

__global__ void matmul_gat1(const float* __restrict__ X, const float* __restrict__ W,
                            unsigned short* __restrict__ out) {
    __shared__ float Xs[32][23];
    __shared__ float Ws[128][23];
    int t = threadIdx.x;
    int r0 = blockIdx.x * 32;
    for (int idx = t; idx < 128 * 21; idx += 256) Ws[idx / 21][idx % 21] = W[idx];
    for (int idx = t; idx < 32 * 21; idx += 256) {
        int r = idx / 21, k = idx % 21;
        Xs[r][k] = (r0 + r < N_NODES) ? X[(size_t)(r0 + r) * 21 + k] : 0.f;
    }
    __syncthreads();
    int f = t & 127, rsub = t >> 7;
    for (int r = rsub; r < 32; r += 2) {
        if (r0 + r >= N_NODES) break;
        float a = 0.f;
#pragma unroll
        for (int k = 0; k < 21; ++k) a += Xs[r][k] * Ws[f][k];
        out[(size_t)(r0 + r) * HD + f] = f2bf(a);
    }
}

// ---------------- W fp32 -> bf16 pre-convert (128x128) ----------------

__global__ void conv_w_bf(const float* __restrict__ W, unsigned short* __restrict__ Wb) {
    int i = blockIdx.x * 256 + threadIdx.x;
    if (i >= 128 * 32) return;
    float4 v = ((const float4*)W)[i];
    ushort4 u = make_ushort4(f2bf(v.x), f2bf(v.y), f2bf(v.z), f2bf(v.w));
    ((ushort4*)Wb)[i] = u;
}

// ---------------- GAT2 linear: MFMA bf16, C = A[N,128] @ W[128,128]^T ----------------

__global__ __launch_bounds__(256) void gemm_mfma(const unsigned short* __restrict__ A,
                                                 const unsigned short* __restrict__ Wb,
                                                 unsigned short* __restrict__ out, int M) {
    __shared__ unsigned short Wlds[128 * 136];
    int t = threadIdx.x;
    for (int u = t; u < 128 * 16; u += 256) {
        int row = u >> 4, seg = u & 15;
        *(ushort8*)&Wlds[row * 136 + seg * 8] = *(const ushort8*)&Wb[row * 128 + seg * 8];
    }
    __syncthreads();
    int wid = t >> 6, L = t & 63;
    int quad = L >> 4, lo = L & 15;
    int m0 = blockIdx.x * 64 + wid * 16;
    short8 afrag[4];
#pragma unroll
    for (int ch = 0; ch < 4; ++ch)
        afrag[ch] = *(const short8*)&A[(size_t)(m0 + lo) * HD + ch * 32 + quad * 8];
#pragma unroll
    for (int ft = 0; ft < 8; ++ft) {
        f32x4 acc = {0.f, 0.f, 0.f, 0.f};
#pragma unroll
        for (int ch = 0; ch < 4; ++ch) {
            short8 b = *(const short8*)&Wlds[(ft * 16 + lo) * 136 + ch * 32 + quad * 8];
            acc = __builtin_amdgcn_mfma_f32_16x16x32_bf16(afrag[ch], b, acc, 0, 0, 0);
        }
#pragma unroll
        for (int r = 0; r < 4; ++r) {
            int m = m0 + quad * 4 + r;
            if (m < M) out[(size_t)m * HD + ft * 16 + lo] = f2bf(acc[r]);
        }
    }
}

// ---------------- per-node alphas (bf16 h) ----------------

__global__ void alpha_kernel(const unsigned short* __restrict__ h, const float* __restrict__ asrc,
                             const float* __restrict__ adst, float* __restrict__ alpha_s,
                             float* __restrict__ alpha_d) {
    int w = (int)((blockIdx.x * (size_t)blockDim.x + threadIdx.x) >> 6);
    int lane = threadIdx.x & 63;
    if (w >= N_NODES) return;
    unsigned int hv = *(const unsigned int*)&h[(size_t)w * HD + lane * 2];
    float hx = bf2f(hv & 0xFFFFu), hy = bf2f(hv >> 16);
    float2 as = *(const float2*)&asrc[lane * 2];
    float2 ad = *(const float2*)&adst[lane * 2];
    float s = hx * as.x + hy * as.y;
    float d = hx * ad.x + hy * ad.y;
    for (int off = 32; off; off >>= 1) {
        s += __shfl_down(s, off);
        d += __shfl_down(d, off);
    }
    if (lane == 0) { alpha_s[w] = s; alpha_d[w] = d; }
}

// ---------------- edge softmax coefficients (wave per dst) ----------------

__global__ void gat_coef(const int* __restrict__ row_ptr, const int* __restrict__ csr_src,
                         const float* __restrict__ alpha_s, const float* __restrict__ alpha_d,
                         float* __restrict__ coef) {
    int w = (int)((blockIdx.x * (size_t)blockDim.x + threadIdx.x) >> 6);
    int lane = threadIdx.x & 63;
    if (w >= N_NODES) return;
    int rs = row_ptr[w], re = row_ptr[w + 1];
    int deg = re - rs;
    float ad = alpha_d[w];
    int i0 = rs + lane;
    bool has = lane < deg;
    float e0 = -1e30f;
    if (has) {
        int s = csr_src[i0];
        float e = alpha_s[s] + ad;
        e0 = (e > 0.f) ? e : 0.2f * e;
    }
    float m = e0;
    if (deg > 64) {
        for (int i = i0 + 64; i < re; i += 64) {
            int s = csr_src[i];
            float e = alpha_s[s] + ad;
            e = (e > 0.f) ? e : 0.2f * e;
            m = fmaxf(m, e);
        }
    }
    for (int off = 32; off; off >>= 1) m = fmaxf(m, __shfl_xor(m, off));
    if (deg <= 64) {
        float ex = has ? __expf(e0 - m) : 0.f;
        float den = ex;
        for (int off = 32; off; off >>= 1) den += __shfl_xor(den, off);
        if (has) coef[i0] = ex / (den + 1e-16f);
    } else {
        float den = 0.f;
        for (int i = i0; i < re; i += 64) {
            int s = csr_src[i];
            float e = alpha_s[s] + ad;
            e = (e > 0.f) ? e : 0.2f * e;
            float ex = __expf(e - m);
            den += ex;
            coef[i] = ex;
        }
        for (int off = 32; off; off >>= 1) den += __shfl_xor(den, off);
        float inv = 1.f / (den + 1e-16f);
        for (int i = i0; i < re; i += 64) coef[i] *= inv;
    }
}

// ---------------- SpMM aggregation: wave per dst, 4 edge-groups x 16 lanes ----------------

template <int BF_OUT>
__global__ void gat_spmm(const unsigned short* __restrict__ h, const int* __restrict__ row_ptr,
                         const int* __restrict__ csr_src, const float* __restrict__ coef,
                         const float* __restrict__ bias, void* __restrict__ outp) {
    int w = (int)((blockIdx.x * (size_t)blockDim.x + threadIdx.x) >> 6);
    int lane = threadIdx.x & 63;
    if (w >= N_NODES) return;
    int grp = lane >> 4, l16 = lane & 15;
    int rs = row_ptr[w], re = row_ptr[w + 1];
    float acc[8] = {0.f, 0.f, 0.f, 0.f, 0.f, 0.f, 0.f, 0.f};
    for (int i = rs + grp; i < re; i += 4) {
        int s = csr_src[i];
        float c = coef[i];
        ushort8 hv = *(const ushort8*)&h[(size_t)s * HD + l16 * 8];
#pragma unroll
        for (int j = 0; j < 8; ++j) acc[j] += c * bf2f(hv[j]);
    }
#pragma unroll
    for (int j = 0; j < 8; ++j) {
        acc[j] += __shfl_xor(acc[j], 16);
        acc[j] += __shfl_xor(acc[j], 32);
    }
    int f0 = l16 * 8 + grp * 2;
    float2 bv = *(const float2*)&bias[f0];
    float vx = fmaxf(acc[grp * 2]     + bv.x, 0.f);
    float vy = fmaxf(acc[grp * 2 + 1] + bv.y, 0.f);
    if (BF_OUT) {
        unsigned short* o = (unsigned short*)outp;
        unsigned int pv = (unsigned int)f2bf(vx) | ((unsigned int)f2bf(vy) << 16);
        *(unsigned int*)&o[(size_t)w * HD + f0] = pv;
    } else {
        float* o = (float*)outp;
        *(float2*)&o[(size_t)w * HD + f0] = make_float2(vx, vy);
    }
}

// ---------------- mean pool per graph (4 node-groups x 16 lanes) ----------------

__global__ void pool_kernel(const float* __restrict__ h, const int* __restrict__ start,
                            float* __restrict__ z) {
    int w = (int)((blockIdx.x * (size_t)blockDim.x + threadIdx.x) >> 6);
    int lane = threadIdx.x & 63;
    if (w >= NB) return;
    int grp = lane >> 4, l16 = lane & 15;
    int s0 = start[w], s1 = start[w + 1];
    float acc[8] = {0.f, 0.f, 0.f, 0.f, 0.f, 0.f, 0.f, 0.f};
    for (int n = s0 + grp; n < s1; n += 4) {
        const float4* p = (const float4*)&h[(size_t)n * HD + l16 * 8];
        float4 a = p[0], b = p[1];
        acc[0] += a.x; acc[1] += a.y; acc[2] += a.z; acc[3] += a.w;
        acc[4] += b.x; acc[5] += b.y; acc[6] += b.z; acc[7] += b.w;
    }
#pragma unroll
    for (int j = 0; j < 8; ++j) {
        acc[j] += __shfl_xor(acc[j], 16);
        acc[j] += __shfl_xor(acc[j], 32);
    }
    float inv = 1.f / fmaxf((float)(s1 - s0), 1.f);
    int f0 = l16 * 8 + grp * 2;
    *(float2*)&z[(size_t)w * 320 + f0] =
        make_float2(acc[grp * 2] * inv, acc[grp * 2 + 1] * inv);
}

// ---------------- split-K small GEMM with atomic accumulate ----------------

__global__ void gemm_split(const float* __restrict__ X, const float* __restrict__ W1,
                           const float* __restrict__ W2, float* __restrict__ out,
                           int K, int F1, int Ftot, int Kc) {
    __shared__ float Xs[16][33];
    __shared__ float Ws[64][33];
    int t = threadIdx.x;
    int r0 = blockIdx.x * 16;
    int fb = blockIdx.y * 64;
    const float* W = (fb < F1) ? (W1 + (size_t)fb * K) : (W2 + (size_t)(fb - F1) * K);
    int k0 = blockIdx.z * Kc;
    int f = t & 63, rsub = t >> 6;
    float acc0 = 0.f, acc1 = 0.f, acc2 = 0.f, acc3 = 0.f;
    for (int kc = k0; kc < k0 + Kc; kc += 32) {
        {
            int idx = t * 2, xr = idx >> 5, xk = idx & 31;
            const float2 v = *(const float2*)&X[(size_t)(r0 + xr) * K + kc + xk];
            Xs[xr][xk] = v.x; Xs[xr][xk + 1] = v.y;
        }
        {
            int wf = t >> 2, wk = (t & 3) * 8;
            const float4* p = (const float4*)&W[(size_t)wf * K + kc + wk];
            float4 a = p[0], b = p[1];
            Ws[wf][wk] = a.x; Ws[wf][wk + 1] = a.y; Ws[wf][wk + 2] = a.z; Ws[wf][wk + 3] = a.w;
            Ws[wf][wk + 4] = b.x; Ws[wf][wk + 5] = b.y; Ws[wf][wk + 6] = b.z; Ws[wf][wk + 7] = b.w;
        }
        __syncthreads();
#pragma unroll
        for (int k = 0; k < 32; ++k) {
            float w = Ws[f][k];
            acc0 += Xs[rsub][k] * w;
            acc1 += Xs[rsub + 4][k] * w;
            acc2 += Xs[rsub + 8][k] * w;
            acc3 += Xs[rsub + 12][k] * w;
        }
        __syncthreads();
    }
    atomicAdd(&out[(size_t)(r0 + rsub) * Ftot + fb + f], acc0);
    atomicAdd(&out[(size_t)(r0 + rsub + 4) * Ftot + fb + f], acc1);
    atomicAdd(&out[(size_t)(r0 + rsub + 8) * Ftot + fb + f], acc2);
    atomicAdd(&out[(size_t)(r0 + rsub + 12) * Ftot + fb + f], acc3);
}

// ---------------- LSTM nonlinearity ----------------

__device__ __forceinline__ float sigmoidf_(float x) { return 1.f / (1.f + __expf(-x)); }

__global__ void lstm_gate(const float* __restrict__ g,
                          const float* __restrict__ bihf, const float* __restrict__ bhhf,
                          const float* __restrict__ bihr, const float* __restrict__ bhhr,
                          float* __restrict__ z) {
    int idx = blockIdx.x * 256 + threadIdx.x;
    if (idx >= NB * 128) return;
    int b = idx >> 7, jj = idx & 127;
    int dir = jj >> 6, j = jj & 63;
    const float* gb = g + (size_t)b * 512 + dir * 256;
    const float* bi = dir ? bihr : bihf;
    const float* bh = dir ? bhhr : bhhf;
    float gi = gb[j]       + bi[j]       + bh[j];
    float gg = gb[128 + j] + bi[128 + j] + bh[128 + j];
    float go = gb[192 + j] + bi[192 + j] + bh[192 + j];
    float c = sigmoidf_(gi) * tanhf(gg);
    z[(size_t)b * 320 + 128 + jj] = sigmoidf_(go) * tanhf(c);
}

// ---------------- tab pre-BN linear ----------------

__global__ void tab_pre(const float* __restrict__ tf, const float* __restrict__ W,
                        const float* __restrict__ bias, float* __restrict__ out) {
    int idx = blockIdx.x * 256 + threadIdx.x;
    if (idx >= NB * 64) return;
    int b = idx >> 6, j = idx & 63;
    const float* x = &tf[(size_t)b * 7];
    const float* w = &W[(size_t)j * 7];
    float a = bias[j];
#pragma unroll
    for (int k = 0; k < 7; ++k) a += x[k] * w[k];
    out[idx] = a;
}

// ---------------- BatchNorm (training stats) + relu ----------------

__global__ void bn_relu_cols(const float* __restrict__ in, int cols,
                             const float* __restrict__ g, const float* __restrict__ b,
                             float* __restrict__ out, int out_stride, int out_col0) {
    int j = blockIdx.x;
    int t = threadIdx.x;
    __shared__ float ssum[256], ssq[256];
    float vals[4];
    float s = 0.f, q = 0.f;
#pragma unroll
    for (int i = 0; i < 4; ++i) {
        float v = in[(size_t)(t + 256 * i) * cols + j];
        vals[i] = v; s += v; q += v * v;
    }
    ssum[t] = s; ssq[t] = q;
    __syncthreads();
    for (int off = 128; off; off >>= 1) {
        if (t < off) { ssum[t] += ssum[t + off]; ssq[t] += ssq[t + off]; }
        __syncthreads();
    }
    float mu = ssum[0] * (1.f / 1024.f);
    float var = ssq[0] * (1.f / 1024.f) - mu * mu;
    float sc = rsqrtf(var + 1e-5f) * g[j];
    float bb = b[j] - mu * sc;
#pragma unroll
    for (int i = 0; i < 4; ++i) {
        float v = vals[i] * sc + bb;
        out[(size_t)(t + 256 * i) * out_stride + out_col0 + j] = fmaxf(v, 0.f);
    }
}

// ---------------- final: relu(z2 + b2) @ fus3_W^T + fus3_b ----------------

__global__ void final_kernel(const float* __restrict__ z2, const float* __restrict__ b2,
                             const float* __restrict__ W, const float* __restrict__ b,
                             float* __restrict__ out) {
    int w = (int)((blockIdx.x * (size_t)blockDim.x + threadIdx.x) >> 6);
    int lane = threadIdx.x & 63;
    if (w >= NB) return;
    float2 zv = *(const float2*)&z2[(size_t)w * 128 + lane * 2];
    float2 bv = *(const float2*)&b2[lane * 2];
    float2 wv = *(const float2*)&W[lane * 2];
    float zx = fmaxf(zv.x + bv.x, 0.f);
    float zy = fmaxf(zv.y + bv.y, 0.f);
    float s = zx * wv.x + zy * wv.y;
    for (int off = 32; off; off >>= 1) s += __shfl_down(s, off);
    if (lane == 0) out[w] = s + b[0];
}

// ---------------- launch ----------------

extern "C" void kernel_launch(void* const* d_in, const int* in_sizes, int n_in,
                              void* d_out, int out_size, void* d_ws, size_t ws_size,
                              hipStream_t stream) {
    const float* x        = (const float*)d_in[0];
    const int*   ei       = (const int*)d_in[1];
    const int*   batch    = (const int*)d_in[2];
    const float* esm      = (const float*)d_in[3];
    const float* tabf     = (const float*)d_in[4];
    const float* gat1_W   = (const float*)d_in[5];
    const float* gat1_as  = (const float*)d_in[6];
    const float* gat1_ad  = (const float*)d_in[7];
    const float* gat1_b   = (const float*)d_in[8];
    const float* gat2_W   = (const float*)d_in[9];
    const float* gat2_as  = (const float*)d_in[10];
    const float* gat2_ad  = (const float*)d_in[11];
    const float* gat2_b   = (const float*)d_in[12];
    const float* Wih_f    = (const float*)d_in[13];
    const float* bih_f    = (const float*)d_in[15];
    const float* bhh_f    = (const float*)d_in[16];
    const float* Wih_r    = (const float*)d_in[17];
    const float* bih_r    = (const float*)d_in[19];
    const float* bhh_r    = (const float*)d_in[20];
    const float* tab_W    = (const float*)d_in[21];
    const float* tab_b    = (const float*)d_in[22];
    const float* tab_g    = (const float*)d_in[23];
    const float* tab_bb   = (const float*)d_in[24];
    const float* fus1_W   = (const float*)d_in[25];
    const float* fus_g    = (const float*)d_in[27];
    const float* fus_bb   = (const float*)d_in[28];
    const float* fus2_W   = (const float*)d_in[29];
    const float* fus2_b   = (const float*)d_in[30];
    const float* fus3_W   = (const float*)d_in[31];
    const float* fus3_b   = (const float*)d_in[32];
    float* out = (float*)d_out;

    char* ws = (char*)d_ws;
    size_t off = 0;
    auto alloc = [&](size_t bytes) -> char* {
        char* p = ws + off;
        off += (bytes + 255) & ~(size_t)255;
        return p;
    };
    unsigned short* h0_bf = (unsigned short*)alloc((size_t)N_PAD * HD * 2);
    unsigned short* hA_bf = (unsigned short*)alloc((size_t)N_PAD * HD * 2);
    unsigned short* h2_bf = (unsigned short*)alloc((size_t)N_PAD * HD * 2);
    float* h_act   = (float*)alloc((size_t)N_NODES * HD * 4);
    float* alpha_s = (float*)alloc((size_t)N_NODES * 4);
    float* alpha_d = (float*)alloc((size_t)N_NODES * 4);
    float* coef    = (float*)alloc((size_t)E_TOT * 4);
    unsigned short* w2bf = (unsigned short*)alloc((size_t)HD * HD * 2);
    int*   row_ptr = (int*)alloc((size_t)(N_NODES + 1) * 4);
    int*   cursor  = (int*)alloc((size_t)N_NODES * 4);
    int*   csr_src = (int*)alloc((size_t)E_TOT * 4);
    int*   gstart  = (int*)alloc((size_t)(NB + 1) * 4);
    float* z       = (float*)alloc((size_t)NB * 320 * 4);
    float* tabpre  = (float*)alloc((size_t)NB * 64 * 4);
    float* z1      = (float*)alloc((size_t)NB * 256 * 4);
    // zero-init group: deg + g_lstm + z1pre + z2 contiguous, one memset
    int*   deg     = (int*)alloc((size_t)N_NODES * 4);
    float* g_lstm  = (float*)alloc((size_t)NB * 512 * 4);
    float* z1pre   = (float*)alloc((size_t)NB * 256 * 4);
    float* z2      = (float*)alloc((size_t)NB * 128 * 4);
    size_t zero_len = (size_t)((char*)z2 + (size_t)NB * 128 * 4 - (char*)deg);
    hipMemsetAsync(deg, 0, zero_len, stream);

    // CSR build
    count_edges<<<(E_TOT + 255) / 256, 256, 0, stream>>>(ei, deg);
    scan_kernel<<<1, 1024, 0, stream>>>(deg, row_ptr, cursor);
    fill_edges<<<(E_TOT + 255) / 256, 256, 0, stream>>>(ei, cursor, csr_src);
    graph_bounds<<<(N_NODES + 255) / 256, 256, 0, stream>>>(batch, gstart);
    conv_w_bf<<<16, 256, 0, stream>>>(gat2_W, w2bf);

    int aggGrid = (N_NODES + 3) / 4;

    // GAT layer 1
    matmul_gat1<<<(N_NODES + 31) / 32, 256, 0, stream>>>(x, gat1_W, h0_bf);
    alpha_kernel<<<aggGrid, 256, 0, stream>>>(h0_bf, gat1_as, gat1_ad, alpha_s, alpha_d);
    gat_coef<<<aggGrid, 256, 0, stream>>>(row_ptr, csr_src, alpha_s, alpha_d, coef);
    gat_spmm<1><<<aggGrid, 256, 0, stream>>>(h0_bf, row_ptr, csr_src, coef, gat1_b, hA_bf);

    // GAT layer 2
    gemm_mfma<<<N_PAD / 64, 256, 0, stream>>>(hA_bf, w2bf, h2_bf, N_NODES);
    alpha_kernel<<<aggGrid, 256, 0, stream>>>(h2_bf, gat2_as, gat2_ad, alpha_s, alpha_d);
    gat_coef<<<aggGrid, 256, 0, stream>>>(row_ptr, csr_src, alpha_s, alpha_d, coef);
    gat_spmm<0><<<aggGrid, 256, 0, stream>>>(h2_bf, row_ptr, csr_src, coef, gat2_b, h_act);

    // mean pool -> z[:, 0:128)
    pool_kernel<<<(NB + 3) / 4, 256, 0, stream>>>(h_act, gstart, z);

    // LSTM gates (f+r fused)
    gemm_split<<<dim3(64, 8, 3), 256, 0, stream>>>(esm, Wih_f, Wih_r, g_lstm, ESM_DIM, 256, 512, 160);
    lstm_gate<<<(NB * 128 + 255) / 256, 256, 0, stream>>>(g_lstm, bih_f, bhh_f, bih_r, bhh_r, z);

    // tab branch
    tab_pre<<<(NB * 64 + 255) / 256, 256, 0, stream>>>(tabf, tab_W, tab_b, tabpre);
    bn_relu_cols<<<64, 256, 0, stream>>>(tabpre, 64, tab_g, tab_bb, z, 320, 256);

    // fusion head
    gemm_split<<<dim3(64, 4, 2), 256, 0, stream>>>(z, fus1_W, nullptr, z1pre, 320, 256, 256, 160);
    bn_relu_cols<<<256, 256, 0, stream>>>(z1pre, 256, fus_g, fus_bb, z1, 256, 0);
    gemm_split<<<dim3(64, 2, 2), 256, 0, stream>>>(z1, fus2_W, nullptr, z2, 256, 128, 128, 128);
    final_kernel<<<(NB + 3) / 4, 256, 0, stream>>>(z2, fus2_b, fus3_W, fus3_b, out);

    (void)in_sizes; (void)n_in; (void)out_size; (void)ws_size;
}

// Round 5
// 356.042 us; speedup vs baseline: 3.7584x; 1.3148x over previous
//
#include <hip/hip_runtime.h>
#include <hip/hip_bf16.h>

#define N_NODES 50000
#define N_PAD   50048
#define N_EDGES 800000
#define E_TOT   850000
#define NB      1024
#define ESM_DIM 480
#define HD      128
#define NBUCK   196          // buckets of 256 dst nodes
#define EPB     3321         // edges per block for 256 blocks

typedef short short8 __attribute__((ext_vector_type(8)));
typedef unsigned short ushort8 __attribute__((ext_vector_type(8)));
typedef float f32x4 __attribute__((ext_vector_type(4)));

__device__ __forceinline__ float bf2f(unsigned int u) {
    union { unsigned int i; float f; } c; c.i = u << 16; return c.f;
}
__device__ __forceinline__ unsigned short f2bf(float f) {
    union { float f; unsigned int i; } c; c.f = f;
    unsigned int i = c.i;
    return (unsigned short)((i + 0x7FFFu + ((i >> 16) & 1u)) >> 16);
}

// ---------------- CSR build: bucketed counting sort ----------------

__global__ void hist1(const int* __restrict__ ei, int* __restrict__ cnt) {
    __shared__ int hist[NBUCK];
    int t = threadIdx.x;
    for (int u = t; u < NBUCK; u += 256) hist[u] = 0;
    __syncthreads();
    int e0 = blockIdx.x * EPB;
    int e1 = (e0 + EPB < E_TOT) ? e0 + EPB : E_TOT;
    for (int e = e0 + t; e < e1; e += 256) {
        int d = (e < N_EDGES) ? ei[N_EDGES + e] : (e - N_EDGES);
        atomicAdd(&hist[d >> 8], 1);
    }
    __syncthreads();
    for (int u = t; u < NBUCK; u += 256) cnt[u * 256 + blockIdx.x] = hist[u];
}

// exclusive scan of n4*4 ints, 1 block x 1024 threads, 4 elems/thread
__global__ void scan4(const int4* __restrict__ in, int4* __restrict__ out, int n4) {
    __shared__ int wsum[16];
    int t = threadIdx.x, lane = t & 63, wid = t >> 6;
    int carry = 0;
    for (int base = 0; base < n4; base += 1024) {
        int i = base + t;
        int4 v = (i < n4) ? in[i] : make_int4(0, 0, 0, 0);
        int s = v.x + v.y + v.z + v.w;
        int sc = s;
#pragma unroll
        for (int off = 1; off < 64; off <<= 1) {
            int n = __shfl_up(sc, off);
            if (lane >= off) sc += n;
        }
        if (lane == 63) wsum[wid] = sc;
        __syncthreads();
        if (t < 16) {
            int x = wsum[t];
#pragma unroll
            for (int off = 1; off < 16; off <<= 1) {
                int n = __shfl_up(x, off);
                if (t >= off) x += n;
            }
            wsum[t] = x;
        }
        __syncthreads();
        int woff = wid ? wsum[wid - 1] : 0;
        int excl = carry + woff + sc - s;
        if (i < n4)
            out[i] = make_int4(excl, excl + v.x, excl + v.x + v.y, excl + v.x + v.y + v.z);
        carry += wsum[15];
        __syncthreads();
    }
}

__global__ void scatter_pairs(const int* __restrict__ ei, const int* __restrict__ cntoff,
                              int* __restrict__ pairs) {
    __shared__ int cur[NBUCK];
    int t = threadIdx.x;
    for (int u = t; u < NBUCK; u += 256) cur[u] = cntoff[u * 256 + blockIdx.x];
    __syncthreads();
    int e0 = blockIdx.x * EPB;
    int e1 = (e0 + EPB < E_TOT) ? e0 + EPB : E_TOT;
    for (int e = e0 + t; e < e1; e += 256) {
        int s, d;
        if (e < N_EDGES) { s = ei[e]; d = ei[N_EDGES + e]; }
        else             { s = d = e - N_EDGES; }
        int pos = atomicAdd(&cur[d >> 8], 1);
        pairs[pos] = s | ((d & 255) << 16);   // s < 65536
    }
}

// per-bucket degree histogram + in-block scan -> row_ptr (no global atomics)
__global__ void bucket_degscan(const int* __restrict__ cntoff, const int* __restrict__ pairs,
                               int* __restrict__ row_ptr) {
    __shared__ int dc[256];
    __shared__ int wt[4];
    int b = blockIdx.x, t = threadIdx.x;
    int rs = cntoff[b * 256];
    int re = (b == NBUCK - 1) ? E_TOT : cntoff[(b + 1) * 256];
    dc[t] = 0;
    __syncthreads();
    for (int i = rs + t; i < re; i += 256) atomicAdd(&dc[pairs[i] >> 16], 1);
    __syncthreads();
    int v = dc[t];
    int lane = t & 63, wid = t >> 6;
    int sc = v;
#pragma unroll
    for (int off = 1; off < 64; off <<= 1) {
        int n = __shfl_up(sc, off);
        if (lane >= off) sc += n;
    }
    if (lane == 63) wt[wid] = sc;
    __syncthreads();
    int pref = 0;
    for (int ww = 0; ww < wid; ++ww) pref += wt[ww];
    int excl = pref + sc - v;
    int node = b * 256 + t;
    if (node <= N_NODES) row_ptr[node] = rs + excl;
}

__global__ void bucket_place(const int* __restrict__ cntoff, const int* __restrict__ pairs,
                             const int* __restrict__ row_ptr, int* __restrict__ csr_src) {
    __shared__ int cur[256];
    int b = blockIdx.x, t = threadIdx.x;
    int rs = cntoff[b * 256];
    int re = (b == NBUCK - 1) ? E_TOT : cntoff[(b + 1) * 256];
    int node = b * 256 + t;
    cur[t] = (node < N_NODES) ? row_ptr[node] : 0;
    __syncthreads();
    for (int i = rs + t; i < re; i += 256) {
        int pk = pairs[i];
        int pos = atomicAdd(&cur[pk >> 16], 1);
        csr_src[pos] = pk & 0xFFFF;
    }
}

// ---------------- graph bounds + W conversion (merged) ----------------

__global__ void bounds_conv(const int* __restrict__ batch, int* __restrict__ start,
                            const float* __restrict__ W, unsigned short* __restrict__ Wb) {
    int b = blockIdx.x, t = threadIdx.x;
    if (b < NBUCK) {
        int i = b * 256 + t;
        if (i >= N_NODES) return;
        int bb = batch[i];
        int bp = (i == 0) ? -1 : batch[i - 1];
        for (int g = bp + 1; g <= bb; ++g) start[g] = i;
        if (i == N_NODES - 1)
            for (int g = bb + 1; g <= NB; ++g) start[g] = N_NODES;
    } else {
        int i = (b - NBUCK) * 256 + t;
        if (i >= 128 * 32) return;
        float4 v = ((const float4*)W)[i];
        ((ushort4*)Wb)[i] = make_ushort4(f2bf(v.x), f2bf(v.y), f2bf(v.z), f2bf(v.w));
    }
}

// ---------------- GAT1 linear + fused alphas ----------------

__global__ void matmul_gat1(const float* __restrict__ X, const float* __restrict__ W,
                            const float* __restrict__ asrc, const float* __restrict__ adst,
                            unsigned short* __restrict__ out,
                            float* __restrict__ alpha_s, float* __restrict__ alpha_d) {
    __shared__ float Xs[32][23];
    __shared__ float Ws[128][23];
    __shared__ float w_as[21], w_ad[21];
    int t = threadIdx.x;
    int r0 = blockIdx.x * 32;
    for (int idx = t; idx < 128 * 21; idx += 256) Ws[idx / 21][idx % 21] = W[idx];
    for (int idx = t; idx < 32 * 21; idx += 256) {
        int r = idx / 21, k = idx % 21;
        Xs[r][k] = (r0 + r < N_NODES) ? X[(size_t)(r0 + r) * 21 + k] : 0.f;
    }
    __syncthreads();
    if (t < 21) {
        float sa = 0.f, sd = 0.f;
        for (int f2 = 0; f2 < 128; ++f2) {
            float wv = Ws[f2][t];
            sa += wv * asrc[f2];
            sd += wv * adst[f2];
        }
        w_as[t] = sa; w_ad[t] = sd;
    }
    __syncthreads();
    int f = t & 127, rsub = t >> 7;
    for (int r = rsub; r < 32; r += 2) {
        if (r0 + r >= N_NODES) break;
        float a = 0.f;
#pragma unroll
        for (int k = 0; k < 21; ++k) a += Xs[r][k] * Ws[f][k];
        out[(size_t)(r0 + r) * HD + f] = f2bf(a);
    }
    if (t < 32 && r0 + t < N_NODES) {
        float sa = 0.f, sd = 0.f;
#pragma unroll
        for (int k = 0; k < 21; ++k) {
            float xv = Xs[t][k];
            sa += xv * w_as[k];
            sd += xv * w_ad[k];
        }
        alpha_s[r0 + t] = sa;
        alpha_d[r0 + t] = sd;
    }
}

// ---------------- GAT2 linear: MFMA + fused alpha epilogue ----------------

__global__ __launch_bounds__(256) void gemm_mfma(const unsigned short* __restrict__ A,
                                                 const unsigned short* __restrict__ Wb,
                                                 const float* __restrict__ asrc,
                                                 const float* __restrict__ adst,
                                                 unsigned short* __restrict__ out,
                                                 float* __restrict__ alpha_s,
                                                 float* __restrict__ alpha_d, int M) {
    __shared__ unsigned short Wlds[128 * 136];
    int t = threadIdx.x;
    for (int u = t; u < 128 * 16; u += 256) {
        int row = u >> 4, seg = u & 15;
        *(ushort8*)&Wlds[row * 136 + seg * 8] = *(const ushort8*)&Wb[row * 128 + seg * 8];
    }
    __syncthreads();
    int wid = t >> 6, L = t & 63;
    int quad = L >> 4, lo = L & 15;
    int m0 = blockIdx.x * 64 + wid * 16;
    short8 afrag[4];
#pragma unroll
    for (int ch = 0; ch < 4; ++ch)
        afrag[ch] = *(const short8*)&A[(size_t)(m0 + lo) * HD + ch * 32 + quad * 8];
    float as_p[4] = {0.f, 0.f, 0.f, 0.f};
    float ad_p[4] = {0.f, 0.f, 0.f, 0.f};
#pragma unroll
    for (int ft = 0; ft < 8; ++ft) {
        f32x4 acc = {0.f, 0.f, 0.f, 0.f};
#pragma unroll
        for (int ch = 0; ch < 4; ++ch) {
            short8 b = *(const short8*)&Wlds[(ft * 16 + lo) * 136 + ch * 32 + quad * 8];
            acc = __builtin_amdgcn_mfma_f32_16x16x32_bf16(afrag[ch], b, acc, 0, 0, 0);
        }
        float asv = asrc[ft * 16 + lo];
        float adv = adst[ft * 16 + lo];
#pragma unroll
        for (int r = 0; r < 4; ++r) {
            int m = m0 + quad * 4 + r;
            if (m < M) out[(size_t)m * HD + ft * 16 + lo] = f2bf(acc[r]);
            as_p[r] += acc[r] * asv;
            ad_p[r] += acc[r] * adv;
        }
    }
#pragma unroll
    for (int off = 1; off < 16; off <<= 1) {
#pragma unroll
        for (int r = 0; r < 4; ++r) {
            as_p[r] += __shfl_xor(as_p[r], off);
            ad_p[r] += __shfl_xor(ad_p[r], off);
        }
    }
    if (lo == 0) {
#pragma unroll
        for (int r = 0; r < 4; ++r) {
            int m = m0 + quad * 4 + r;
            if (m < M) { alpha_s[m] = as_p[r]; alpha_d[m] = ad_p[r]; }
        }
    }
}

// ---------------- fused edge-softmax + SpMM (wave per dst) ----------------

template <int BF_OUT>
__global__ void gat_spmm(const unsigned short* __restrict__ h, const int* __restrict__ row_ptr,
                         const int* __restrict__ csr_src, const float* __restrict__ alpha_s,
                         const float* __restrict__ alpha_d, const float* __restrict__ bias,
                         void* __restrict__ outp) {
    int w = (int)((blockIdx.x * (size_t)blockDim.x + threadIdx.x) >> 6);
    int lane = threadIdx.x & 63;
    if (w >= N_NODES) return;
    int grp = lane >> 4, l16 = lane & 15;
    int rs = row_ptr[w], re = row_ptr[w + 1];
    int deg = re - rs;
    float ad = alpha_d[w];
    float acc[8] = {0.f, 0.f, 0.f, 0.f, 0.f, 0.f, 0.f, 0.f};
    if (deg <= 64) {
        int s_reg = 0;
        float e = -1e30f;
        if (lane < deg) {
            s_reg = csr_src[rs + lane];
            float t0 = alpha_s[s_reg] + ad;
            e = (t0 > 0.f) ? t0 : 0.2f * t0;
        }
        float m = e;
#pragma unroll
        for (int off = 32; off; off >>= 1) m = fmaxf(m, __shfl_xor(m, off));
        float ex = (lane < deg) ? __expf(e - m) : 0.f;
        float den = ex;
#pragma unroll
        for (int off = 32; off; off >>= 1) den += __shfl_xor(den, off);
        float coef = ex / (den + 1e-16f);
        for (int i = rs + grp; i < re; i += 4) {
            int idx = i - rs;
            float c = __shfl(coef, idx);
            int s = __shfl(s_reg, idx);
            ushort8 hv = *(const ushort8*)&h[(size_t)s * HD + l16 * 8];
#pragma unroll
            for (int j = 0; j < 8; ++j) acc[j] += c * bf2f(hv[j]);
        }
    } else {
        float m = -1e30f;
        for (int i = rs + lane; i < re; i += 64) {
            int s = csr_src[i];
            float t0 = alpha_s[s] + ad;
            t0 = (t0 > 0.f) ? t0 : 0.2f * t0;
            m = fmaxf(m, t0);
        }
#pragma unroll
        for (int off = 32; off; off >>= 1) m = fmaxf(m, __shfl_xor(m, off));
        float den = 0.f;
        for (int i = rs + lane; i < re; i += 64) {
            int s = csr_src[i];
            float t0 = alpha_s[s] + ad;
            t0 = (t0 > 0.f) ? t0 : 0.2f * t0;
            den += __expf(t0 - m);
        }
#pragma unroll
        for (int off = 32; off; off >>= 1) den += __shfl_xor(den, off);
        float inv = 1.f / (den + 1e-16f);
        for (int i = rs + grp; i < re; i += 4) {
            int s = csr_src[i];
            float t0 = alpha_s[s] + ad;
            t0 = (t0 > 0.f) ? t0 : 0.2f * t0;
            float c = __expf(t0 - m) * inv;
            ushort8 hv = *(const ushort8*)&h[(size_t)s * HD + l16 * 8];
#pragma unroll
            for (int j = 0; j < 8; ++j) acc[j] += c * bf2f(hv[j]);
        }
    }
#pragma unroll
    for (int j = 0; j < 8; ++j) {
        acc[j] += __shfl_xor(acc[j], 16);
        acc[j] += __shfl_xor(acc[j], 32);
    }
    int f0 = l16 * 8 + grp * 2;
    float2 bv = *(const float2*)&bias[f0];
    float vx = fmaxf(acc[grp * 2]     + bv.x, 0.f);
    float vy = fmaxf(acc[grp * 2 + 1] + bv.y, 0.f);
    if (BF_OUT) {
        unsigned short* o = (unsigned short*)outp;
        unsigned int pv = (unsigned int)f2bf(vx) | ((unsigned int)f2bf(vy) << 16);
        *(unsigned int*)&o[(size_t)w * HD + f0] = pv;
    } else {
        float* o = (float*)outp;
        *(float2*)&o[(size_t)w * HD + f0] = make_float2(vx, vy);
    }
}

// ---------------- mean pool per graph ----------------

__global__ void pool_kernel(const float* __restrict__ h, const int* __restrict__ start,
                            float* __restrict__ z) {
    int w = (int)((blockIdx.x * (size_t)blockDim.x + threadIdx.x) >> 6);
    int lane = threadIdx.x & 63;
    if (w >= NB) return;
    int grp = lane >> 4, l16 = lane & 15;
    int s0 = start[w], s1 = start[w + 1];
    float acc[8] = {0.f, 0.f, 0.f, 0.f, 0.f, 0.f, 0.f, 0.f};
    for (int n = s0 + grp; n < s1; n += 4) {
        const float4* p = (const float4*)&h[(size_t)n * HD + l16 * 8];
        float4 a = p[0], b = p[1];
        acc[0] += a.x; acc[1] += a.y; acc[2] += a.z; acc[3] += a.w;
        acc[4] += b.x; acc[5] += b.y; acc[6] += b.z; acc[7] += b.w;
    }
#pragma unroll
    for (int j = 0; j < 8; ++j) {
        acc[j] += __shfl_xor(acc[j], 16);
        acc[j] += __shfl_xor(acc[j], 32);
    }
    float inv = 1.f / fmaxf((float)(s1 - s0), 1.f);
    int f0 = l16 * 8 + grp * 2;
    *(float2*)&z[(size_t)w * 320 + f0] =
        make_float2(acc[grp * 2] * inv, acc[grp * 2 + 1] * inv);
}

// ---------------- split-K small GEMM with atomic accumulate ----------------

__global__ void gemm_split(const float* __restrict__ X, const float* __restrict__ W1,
                           const float* __restrict__ W2, float* __restrict__ out,
                           int K, int F1, int Ftot, int Kc) {
    __shared__ float Xs[16][33];
    __shared__ float Ws[64][33];
    int t = threadIdx.x;
    int r0 = blockIdx.x * 16;
    int fb = blockIdx.y * 64;
    const float* W = (fb < F1) ? (W1 + (size_t)fb * K) : (W2 + (size_t)(fb - F1) * K);
    int k0 = blockIdx.z * Kc;
    int f = t & 63, rsub = t >> 6;
    float acc0 = 0.f, acc1 = 0.f, acc2 = 0.f, acc3 = 0.f;
    for (int kc = k0; kc < k0 + Kc; kc += 32) {
        {
            int idx = t * 2, xr = idx >> 5, xk = idx & 31;
            const float2 v = *(const float2*)&X[(size_t)(r0 + xr) * K + kc + xk];
            Xs[xr][xk] = v.x; Xs[xr][xk + 1] = v.y;
        }
        {
            int wf = t >> 2, wk = (t & 3) * 8;
            const float4* p = (const float4*)&W[(size_t)wf * K + kc + wk];
            float4 a = p[0], b = p[1];
            Ws[wf][wk] = a.x; Ws[wf][wk + 1] = a.y; Ws[wf][wk + 2] = a.z; Ws[wf][wk + 3] = a.w;
            Ws[wf][wk + 4] = b.x; Ws[wf][wk + 5] = b.y; Ws[wf][wk + 6] = b.z; Ws[wf][wk + 7] = b.w;
        }
        __syncthreads();
#pragma unroll
        for (int k = 0; k < 32; ++k) {
            float w = Ws[f][k];
            acc0 += Xs[rsub][k] * w;
            acc1 += Xs[rsub + 4][k] * w;
            acc2 += Xs[rsub + 8][k] * w;
            acc3 += Xs[rsub + 12][k] * w;
        }
        __syncthreads();
    }
    atomicAdd(&out[(size_t)(r0 + rsub) * Ftot + fb + f], acc0);
    atomicAdd(&out[(size_t)(r0 + rsub + 4) * Ftot + fb + f], acc1);
    atomicAdd(&out[(size_t)(r0 + rsub + 8) * Ftot + fb + f], acc2);
    atomicAdd(&out[(size_t)(r0 + rsub + 12) * Ftot + fb + f], acc3);
}

// ---------------- LSTM nonlinearity ----------------

__device__ __forceinline__ float sigmoidf_(float x) { return 1.f / (1.f + __expf(-x)); }

__global__ void lstm_gate(const float* __restrict__ g,
                          const float* __restrict__ bihf, const float* __restrict__ bhhf,
                          const float* __restrict__ bihr, const float* __restrict__ bhhr,
                          float* __restrict__ z) {
    int idx = blockIdx.x * 256 + threadIdx.x;
    if (idx >= NB * 128) return;
    int b = idx >> 7, jj = idx & 127;
    int dir = jj >> 6, j = jj & 63;
    const float* gb = g + (size_t)b * 512 + dir * 256;
    const float* bi = dir ? bihr : bihf;
    const float* bh = dir ? bhhr : bhhf;
    float gi = gb[j]       + bi[j]       + bh[j];
    float gg = gb[128 + j] + bi[128 + j] + bh[128 + j];
    float go = gb[192 + j] + bi[192 + j] + bh[192 + j];
    float c = sigmoidf_(gi) * tanhf(gg);
    z[(size_t)b * 320 + 128 + jj] = sigmoidf_(go) * tanhf(c);
}

// ---------------- tab branch fused: linear + BN + relu (single block) ----------------

__global__ __launch_bounds__(1024) void tab_fused(const float* __restrict__ tf,
                                                  const float* __restrict__ W,
                                                  const float* __restrict__ bias,
                                                  const float* __restrict__ g,
                                                  const float* __restrict__ b,
                                                  float* __restrict__ z) {
    __shared__ float ssum[16][64];
    __shared__ float ssq[16][64];
    int t = threadIdx.x;
    int rg = t >> 6, j = t & 63;
    float Wj[7];
#pragma unroll
    for (int k = 0; k < 7; ++k) Wj[k] = W[j * 7 + k];
    float bj = bias[j];
    float pre[64];
    float s = 0.f, q = 0.f;
    for (int rr = 0; rr < 64; ++rr) {
        int row = rg * 64 + rr;
        const float* x = &tf[(size_t)row * 7];
        float a = bj;
#pragma unroll
        for (int k = 0; k < 7; ++k) a += x[k] * Wj[k];
        pre[rr] = a; s += a; q += a * a;
    }
    ssum[rg][j] = s; ssq[rg][j] = q;
    __syncthreads();
    for (int off = 8; off; off >>= 1) {
        if (rg < off) { ssum[rg][j] += ssum[rg + off][j]; ssq[rg][j] += ssq[rg + off][j]; }
        __syncthreads();
    }
    float mu = ssum[0][j] * (1.f / 1024.f);
    float var = ssq[0][j] * (1.f / 1024.f) - mu * mu;
    float sc = rsqrtf(var + 1e-5f) * g[j];
    float bb = b[j] - mu * sc;
    for (int rr = 0; rr < 64; ++rr) {
        int row = rg * 64 + rr;
        z[(size_t)row * 320 + 256 + j] = fmaxf(pre[rr] * sc + bb, 0.f);
    }
}

// ---------------- BatchNorm (training stats) + relu ----------------

__global__ void bn_relu_cols(const float* __restrict__ in, int cols,
                             const float* __restrict__ g, const float* __restrict__ b,
                             float* __restrict__ out, int out_stride, int out_col0) {
    int j = blockIdx.x;
    int t = threadIdx.x;
    __shared__ float ssum[256], ssq[256];
    float vals[4];
    float s = 0.f, q = 0.f;
#pragma unroll
    for (int i = 0; i < 4; ++i) {
        float v = in[(size_t)(t + 256 * i) * cols + j];
        vals[i] = v; s += v; q += v * v;
    }
    ssum[t] = s; ssq[t] = q;
    __syncthreads();
    for (int off = 128; off; off >>= 1) {
        if (t < off) { ssum[t] += ssum[t + off]; ssq[t] += ssq[t + off]; }
        __syncthreads();
    }
    float mu = ssum[0] * (1.f / 1024.f);
    float var = ssq[0] * (1.f / 1024.f) - mu * mu;
    float sc = rsqrtf(var + 1e-5f) * g[j];
    float bb = b[j] - mu * sc;
#pragma unroll
    for (int i = 0; i < 4; ++i) {
        float v = vals[i] * sc + bb;
        out[(size_t)(t + 256 * i) * out_stride + out_col0 + j] = fmaxf(v, 0.f);
    }
}

// ---------------- final: relu(z2 + b2) @ fus3_W^T + fus3_b ----------------

__global__ void final_kernel(const float* __restrict__ z2, const float* __restrict__ b2,
                             const float* __restrict__ W, const float* __restrict__ b,
                             float* __restrict__ out) {
    int w = (int)((blockIdx.x * (size_t)blockDim.x + threadIdx.x) >> 6);
    int lane = threadIdx.x & 63;
    if (w >= NB) return;
    float2 zv = *(const float2*)&z2[(size_t)w * 128 + lane * 2];
    float2 bv = *(const float2*)&b2[lane * 2];
    float2 wv = *(const float2*)&W[lane * 2];
    float zx = fmaxf(zv.x + bv.x, 0.f);
    float zy = fmaxf(zv.y + bv.y, 0.f);
    float s = zx * wv.x + zy * wv.y;
    for (int off = 32; off; off >>= 1) s += __shfl_down(s, off);
    if (lane == 0) out[w] = s + b[0];
}

// ---------------- launch ----------------

extern "C" void kernel_launch(void* const* d_in, const int* in_sizes, int n_in,
                              void* d_out, int out_size, void* d_ws, size_t ws_size,
                              hipStream_t stream) {
    const float* x        = (const float*)d_in[0];
    const int*   ei       = (const int*)d_in[1];
    const int*   batch    = (const int*)d_in[2];
    const float* esm      = (const float*)d_in[3];
    const float* tabf     = (const float*)d_in[4];
    const float* gat1_W   = (const float*)d_in[5];
    const float* gat1_as  = (const float*)d_in[6];
    const float* gat1_ad  = (const float*)d_in[7];
    const float* gat1_b   = (const float*)d_in[8];
    const float* gat2_W   = (const float*)d_in[9];
    const float* gat2_as  = (const float*)d_in[10];
    const float* gat2_ad  = (const float*)d_in[11];
    const float* gat2_b   = (const float*)d_in[12];
    const float* Wih_f    = (const float*)d_in[13];
    const float* bih_f    = (const float*)d_in[15];
    const float* bhh_f    = (const float*)d_in[16];
    const float* Wih_r    = (const float*)d_in[17];
    const float* bih_r    = (const float*)d_in[19];
    const float* bhh_r    = (const float*)d_in[20];
    const float* tab_W    = (const float*)d_in[21];
    const float* tab_b    = (const float*)d_in[22];
    const float* tab_g    = (const float*)d_in[23];
    const float* tab_bb   = (const float*)d_in[24];
    const float* fus1_W   = (const float*)d_in[25];
    const float* fus_g    = (const float*)d_in[27];
    const float* fus_bb   = (const float*)d_in[28];
    const float* fus2_W   = (const float*)d_in[29];
    const float* fus2_b   = (const float*)d_in[30];
    const float* fus3_W   = (const float*)d_in[31];
    const float* fus3_b   = (const float*)d_in[32];
    float* out = (float*)d_out;

    char* ws = (char*)d_ws;
    size_t off = 0;
    auto alloc = [&](size_t bytes) -> char* {
        char* p = ws + off;
        off += (bytes + 255) & ~(size_t)255;
        return p;
    };
    unsigned short* h0_bf = (unsigned short*)alloc((size_t)N_PAD * HD * 2);
    unsigned short* hA_bf = (unsigned short*)alloc((size_t)N_PAD * HD * 2);
    unsigned short* h2_bf = (unsigned short*)alloc((size_t)N_PAD * HD * 2);
    float* h_act   = (float*)alloc((size_t)N_NODES * HD * 4);
    float* alpha_s = (float*)alloc((size_t)N_NODES * 4);
    float* alpha_d = (float*)alloc((size_t)N_NODES * 4);
    unsigned short* w2bf = (unsigned short*)alloc((size_t)HD * HD * 2);
    int*   row_ptr = (int*)alloc((size_t)(N_NODES + 1) * 4);
    int*   csr_src = (int*)alloc((size_t)E_TOT * 4);
    int*   pairs   = (int*)alloc((size_t)E_TOT * 4);
    int*   cnt     = (int*)alloc((size_t)NBUCK * 256 * 4);
    int*   cntoff  = (int*)alloc((size_t)NBUCK * 256 * 4);
    int*   gstart  = (int*)alloc((size_t)(NB + 1) * 4);
    float* z       = (float*)alloc((size_t)NB * 320 * 4);
    float* z1      = (float*)alloc((size_t)NB * 256 * 4);
    // zero-init group (contiguous, one memset)
    float* g_lstm  = (float*)alloc((size_t)NB * 512 * 4);
    float* z1pre   = (float*)alloc((size_t)NB * 256 * 4);
    float* z2      = (float*)alloc((size_t)NB * 128 * 4);
    size_t zero_len = (size_t)((char*)z2 + (size_t)NB * 128 * 4 - (char*)g_lstm);
    hipMemsetAsync(g_lstm, 0, zero_len, stream);

    // CSR build (bucketed counting sort, no global atomics)
    hist1<<<256, 256, 0, stream>>>(ei, cnt);
    scan4<<<1, 1024, 0, stream>>>((const int4*)cnt, (int4*)cntoff, NBUCK * 64);
    scatter_pairs<<<256, 256, 0, stream>>>(ei, cntoff, pairs);
    bucket_degscan<<<NBUCK, 256, 0, stream>>>(cntoff, pairs, row_ptr);
    bucket_place<<<NBUCK, 256, 0, stream>>>(cntoff, pairs, row_ptr, csr_src);
    bounds_conv<<<NBUCK + 16, 256, 0, stream>>>(batch, gstart, gat2_W, w2bf);

    int aggGrid = (N_NODES + 3) / 4;

    // GAT layer 1 (alphas fused into linear)
    matmul_gat1<<<(N_NODES + 31) / 32, 256, 0, stream>>>(x, gat1_W, gat1_as, gat1_ad,
                                                          h0_bf, alpha_s, alpha_d);
    gat_spmm<1><<<aggGrid, 256, 0, stream>>>(h0_bf, row_ptr, csr_src, alpha_s, alpha_d,
                                             gat1_b, hA_bf);

    // GAT layer 2 (alphas fused into MFMA epilogue)
    gemm_mfma<<<N_PAD / 64, 256, 0, stream>>>(hA_bf, w2bf, gat2_as, gat2_ad,
                                              h2_bf, alpha_s, alpha_d, N_NODES);
    gat_spmm<0><<<aggGrid, 256, 0, stream>>>(h2_bf, row_ptr, csr_src, alpha_s, alpha_d,
                                             gat2_b, h_act);

    // mean pool -> z[:, 0:128)
    pool_kernel<<<(NB + 3) / 4, 256, 0, stream>>>(h_act, gstart, z);

    // LSTM gates (f+r fused)
    gemm_split<<<dim3(64, 8, 3), 256, 0, stream>>>(esm, Wih_f, Wih_r, g_lstm, ESM_DIM, 256, 512, 160);
    lstm_gate<<<(NB * 128 + 255) / 256, 256, 0, stream>>>(g_lstm, bih_f, bhh_f, bih_r, bhh_r, z);

    // tab branch (fused linear+BN+relu, single block)
    tab_fused<<<1, 1024, 0, stream>>>(tabf, tab_W, tab_b, tab_g, tab_bb, z);

    // fusion head
    gemm_split<<<dim3(64, 4, 2), 256, 0, stream>>>(z, fus1_W, nullptr, z1pre, 320, 256, 256, 160);
    bn_relu_cols<<<256, 256, 0, stream>>>(z1pre, 256, fus_g, fus_bb, z1, 256, 0);
    gemm_split<<<dim3(64, 2, 2), 256, 0, stream>>>(z1, fus2_W, nullptr, z2, 256, 128, 128, 128);
    final_kernel<<<(NB + 3) / 4, 256, 0, stream>>>(z2, fus2_b, fus3_W, fus3_b, out);

    (void)in_sizes; (void)n_in; (void)out_size; (void)ws_size;
}

// Round 6
// 350.987 us; speedup vs baseline: 3.8125x; 1.0144x over previous
//
#include <hip/hip_runtime.h>
#include <hip/hip_bf16.h>

#define N_NODES 50000
#define N_PAD   50048
#define N_EDGES 800000
#define E_TOT   850000
#define NB      1024
#define ESM_DIM 480
#define HD      128
#define NBUCK   196          // buckets of 256 dst nodes
#define EPB     3321         // edges per block for 256 blocks

typedef short short8 __attribute__((ext_vector_type(8)));
typedef unsigned short ushort8 __attribute__((ext_vector_type(8)));
typedef float f32x4 __attribute__((ext_vector_type(4)));

__device__ __forceinline__ float bf2f(unsigned int u) {
    union { unsigned int i; float f; } c; c.i = u << 16; return c.f;
}
__device__ __forceinline__ unsigned short f2bf(float f) {
    union { float f; unsigned int i; } c; c.f = f;
    unsigned int i = c.i;
    return (unsigned short)((i + 0x7FFFu + ((i >> 16) & 1u)) >> 16);
}

// ---------------- CSR build: bucketed counting sort ----------------

__global__ void hist1(const int* __restrict__ ei, int* __restrict__ cnt) {
    __shared__ int hist[NBUCK];
    int t = threadIdx.x;
    for (int u = t; u < NBUCK; u += 256) hist[u] = 0;
    __syncthreads();
    int e0 = blockIdx.x * EPB;
    int e1 = (e0 + EPB < E_TOT) ? e0 + EPB : E_TOT;
    for (int e = e0 + t; e < e1; e += 256) {
        int d = (e < N_EDGES) ? ei[N_EDGES + e] : (e - N_EDGES);
        atomicAdd(&hist[d >> 8], 1);
    }
    __syncthreads();
    for (int u = t; u < NBUCK; u += 256) cnt[u * 256 + blockIdx.x] = hist[u];
}

// exclusive scan of n4*4 ints, 1 block x 1024 threads
__global__ void scan4(const int4* __restrict__ in, int4* __restrict__ out, int n4) {
    __shared__ int wsum[16];
    int t = threadIdx.x, lane = t & 63, wid = t >> 6;
    int carry = 0;
    for (int base = 0; base < n4; base += 1024) {
        int i = base + t;
        int4 v = (i < n4) ? in[i] : make_int4(0, 0, 0, 0);
        int s = v.x + v.y + v.z + v.w;
        int sc = s;
#pragma unroll
        for (int off = 1; off < 64; off <<= 1) {
            int n = __shfl_up(sc, off);
            if (lane >= off) sc += n;
        }
        if (lane == 63) wsum[wid] = sc;
        __syncthreads();
        if (t < 16) {
            int x = wsum[t];
#pragma unroll
            for (int off = 1; off < 16; off <<= 1) {
                int n = __shfl_up(x, off);
                if (t >= off) x += n;
            }
            wsum[t] = x;
        }
        __syncthreads();
        int woff = wid ? wsum[wid - 1] : 0;
        int excl = carry + woff + sc - s;
        if (i < n4)
            out[i] = make_int4(excl, excl + v.x, excl + v.x + v.y, excl + v.x + v.y + v.z);
        carry += wsum[15];
        __syncthreads();
    }
}

__global__ void scatter_pairs(const int* __restrict__ ei, const int* __restrict__ cntoff,
                              int* __restrict__ pairs) {
    __shared__ int cur[NBUCK];
    int t = threadIdx.x;
    for (int u = t; u < NBUCK; u += 256) cur[u] = cntoff[u * 256 + blockIdx.x];
    __syncthreads();
    int e0 = blockIdx.x * EPB;
    int e1 = (e0 + EPB < E_TOT) ? e0 + EPB : E_TOT;
    for (int e = e0 + t; e < e1; e += 256) {
        int s, d;
        if (e < N_EDGES) { s = ei[e]; d = ei[N_EDGES + e]; }
        else             { s = d = e - N_EDGES; }
        int pos = atomicAdd(&cur[d >> 8], 1);
        pairs[pos] = s | ((d & 255) << 16);   // s < 65536
    }
}

// merged: per-bucket degree histogram + scan -> row_ptr, then in-bucket placement
__global__ void bucket_csr(const int* __restrict__ cntoff, const int* __restrict__ pairs,
                           int* __restrict__ row_ptr, int* __restrict__ csr_src) {
    __shared__ int dc[256];
    __shared__ int wt[4];
    __shared__ int cur[256];
    int b = blockIdx.x, t = threadIdx.x;
    int rs = cntoff[b * 256];
    int re = (b == NBUCK - 1) ? E_TOT : cntoff[(b + 1) * 256];
    dc[t] = 0;
    __syncthreads();
    for (int i = rs + t; i < re; i += 256) atomicAdd(&dc[pairs[i] >> 16], 1);
    __syncthreads();
    int v = dc[t];
    int lane = t & 63, wid = t >> 6;
    int sc = v;
#pragma unroll
    for (int off = 1; off < 64; off <<= 1) {
        int n = __shfl_up(sc, off);
        if (lane >= off) sc += n;
    }
    if (lane == 63) wt[wid] = sc;
    __syncthreads();
    int pref = 0;
    for (int ww = 0; ww < wid; ++ww) pref += wt[ww];
    int excl = pref + sc - v;
    int node = b * 256 + t;
    if (node <= N_NODES) row_ptr[node] = rs + excl;
    cur[t] = rs + excl;
    __syncthreads();
    for (int i = rs + t; i < re; i += 256) {
        int pk = pairs[i];
        int pos = atomicAdd(&cur[pk >> 16], 1);
        csr_src[pos] = pk & 0xFFFF;
    }
}

// ---------------- graph bounds + W conversion (merged) ----------------

__global__ void bounds_conv(const int* __restrict__ batch, int* __restrict__ start,
                            const float* __restrict__ W, unsigned short* __restrict__ Wb) {
    int b = blockIdx.x, t = threadIdx.x;
    if (b < NBUCK) {
        int i = b * 256 + t;
        if (i >= N_NODES) return;
        int bb = batch[i];
        int bp = (i == 0) ? -1 : batch[i - 1];
        for (int g = bp + 1; g <= bb; ++g) start[g] = i;
        if (i == N_NODES - 1)
            for (int g = bb + 1; g <= NB; ++g) start[g] = N_NODES;
    } else {
        int i = (b - NBUCK) * 256 + t;
        if (i >= 128 * 32) return;
        float4 v = ((const float4*)W)[i];
        ((ushort4*)Wb)[i] = make_ushort4(f2bf(v.x), f2bf(v.y), f2bf(v.z), f2bf(v.w));
    }
}

// ---------------- GAT1 linear + fused alphas (register-W inner loop) ----------------

__global__ void matmul_gat1(const float* __restrict__ X, const float* __restrict__ W,
                            const float* __restrict__ asrc, const float* __restrict__ adst,
                            unsigned short* __restrict__ out,
                            float* __restrict__ alpha_s, float* __restrict__ alpha_d) {
    __shared__ float Xs[32][23];
    __shared__ float Ws[128][21];
    __shared__ float w_as[21], w_ad[21];
    int t = threadIdx.x;
    int r0 = blockIdx.x * 32;
    for (int idx = t; idx < 128 * 21; idx += 256) Ws[idx / 21][idx % 21] = W[idx];
    for (int idx = t; idx < 32 * 21; idx += 256) {
        int r = idx / 21, k = idx % 21;
        Xs[r][k] = (r0 + r < N_NODES) ? X[(size_t)(r0 + r) * 21 + k] : 0.f;
    }
    __syncthreads();
    if (t < 21) {
        float sa = 0.f, sd = 0.f;
        for (int f2 = 0; f2 < 128; ++f2) {
            float wv = Ws[f2][t];
            sa += wv * asrc[f2];
            sd += wv * adst[f2];
        }
        w_as[t] = sa; w_ad[t] = sd;
    }
    int f = t & 127, rsub = t >> 7;
    float Wreg[21];
#pragma unroll
    for (int k = 0; k < 21; ++k) Wreg[k] = Ws[f][k];
#pragma unroll 4
    for (int r = rsub; r < 32; r += 2) {
        if (r0 + r >= N_NODES) break;
        float a = 0.f;
#pragma unroll
        for (int k = 0; k < 21; ++k) a += Xs[r][k] * Wreg[k];
        out[(size_t)(r0 + r) * HD + f] = f2bf(a);
    }
    __syncthreads();
    if (t < 32 && r0 + t < N_NODES) {
        float sa = 0.f, sd = 0.f;
#pragma unroll
        for (int k = 0; k < 21; ++k) {
            float xv = Xs[t][k];
            sa += xv * w_as[k];
            sd += xv * w_ad[k];
        }
        alpha_s[r0 + t] = sa;
        alpha_d[r0 + t] = sd;
    }
}

// ---------------- GAT2 linear: MFMA + fused alpha epilogue ----------------

__global__ __launch_bounds__(256) void gemm_mfma(const unsigned short* __restrict__ A,
                                                 const unsigned short* __restrict__ Wb,
                                                 const float* __restrict__ asrc,
                                                 const float* __restrict__ adst,
                                                 unsigned short* __restrict__ out,
                                                 float* __restrict__ alpha_s,
                                                 float* __restrict__ alpha_d, int M) {
    __shared__ unsigned short Wlds[128 * 136];
    int t = threadIdx.x;
    for (int u = t; u < 128 * 16; u += 256) {
        int row = u >> 4, seg = u & 15;
        *(ushort8*)&Wlds[row * 136 + seg * 8] = *(const ushort8*)&Wb[row * 128 + seg * 8];
    }
    __syncthreads();
    int wid = t >> 6, L = t & 63;
    int quad = L >> 4, lo = L & 15;
    int m0 = blockIdx.x * 64 + wid * 16;
    short8 afrag[4];
#pragma unroll
    for (int ch = 0; ch < 4; ++ch)
        afrag[ch] = *(const short8*)&A[(size_t)(m0 + lo) * HD + ch * 32 + quad * 8];
    float as_p[4] = {0.f, 0.f, 0.f, 0.f};
    float ad_p[4] = {0.f, 0.f, 0.f, 0.f};
#pragma unroll
    for (int ft = 0; ft < 8; ++ft) {
        f32x4 acc = {0.f, 0.f, 0.f, 0.f};
#pragma unroll
        for (int ch = 0; ch < 4; ++ch) {
            short8 b = *(const short8*)&Wlds[(ft * 16 + lo) * 136 + ch * 32 + quad * 8];
            acc = __builtin_amdgcn_mfma_f32_16x16x32_bf16(afrag[ch], b, acc, 0, 0, 0);
        }
        float asv = asrc[ft * 16 + lo];
        float adv = adst[ft * 16 + lo];
#pragma unroll
        for (int r = 0; r < 4; ++r) {
            int m = m0 + quad * 4 + r;
            if (m < M) out[(size_t)m * HD + ft * 16 + lo] = f2bf(acc[r]);
            as_p[r] += acc[r] * asv;
            ad_p[r] += acc[r] * adv;
        }
    }
#pragma unroll
    for (int off = 1; off < 16; off <<= 1) {
#pragma unroll
        for (int r = 0; r < 4; ++r) {
            as_p[r] += __shfl_xor(as_p[r], off);
            ad_p[r] += __shfl_xor(ad_p[r], off);
        }
    }
    if (lo == 0) {
#pragma unroll
        for (int r = 0; r < 4; ++r) {
            int m = m0 + quad * 4 + r;
            if (m < M) { alpha_s[m] = as_p[r]; alpha_d[m] = ad_p[r]; }
        }
    }
}

// ---------------- fused edge-softmax + SpMM (wave per dst, 2x edge ILP) ----------------

__global__ void gat_spmm(const unsigned short* __restrict__ h, const int* __restrict__ row_ptr,
                         const int* __restrict__ csr_src, const float* __restrict__ alpha_s,
                         const float* __restrict__ alpha_d, const float* __restrict__ bias,
                         unsigned short* __restrict__ outp) {
    int w = (int)((blockIdx.x * (size_t)blockDim.x + threadIdx.x) >> 6);
    int lane = threadIdx.x & 63;
    if (w >= N_NODES) return;
    int grp = lane >> 4, l16 = lane & 15;
    int rs = row_ptr[w], re = row_ptr[w + 1];
    int deg = re - rs;
    float ad = alpha_d[w];
    float acc[8] = {0.f, 0.f, 0.f, 0.f, 0.f, 0.f, 0.f, 0.f};
    if (deg <= 64) {
        int s_reg = 0;
        float e = -1e30f;
        if (lane < deg) {
            s_reg = csr_src[rs + lane];
            float t0 = alpha_s[s_reg] + ad;
            e = (t0 > 0.f) ? t0 : 0.2f * t0;
        }
        float m = e;
#pragma unroll
        for (int off = 32; off; off >>= 1) m = fmaxf(m, __shfl_xor(m, off));
        float ex = (lane < deg) ? __expf(e - m) : 0.f;
        float den = ex;
#pragma unroll
        for (int off = 32; off; off >>= 1) den += __shfl_xor(den, off);
        float coef = ex / (den + 1e-16f);
        int i = rs + grp;
        for (; i + 4 < re; i += 8) {
            int idx = i - rs;
            float c0 = __shfl(coef, idx);
            int   s0 = __shfl(s_reg, idx);
            float c1 = __shfl(coef, idx + 4);
            int   s1 = __shfl(s_reg, idx + 4);
            ushort8 h0 = *(const ushort8*)&h[(size_t)s0 * HD + l16 * 8];
            ushort8 h1 = *(const ushort8*)&h[(size_t)s1 * HD + l16 * 8];
#pragma unroll
            for (int j = 0; j < 8; ++j) acc[j] += c0 * bf2f(h0[j]);
#pragma unroll
            for (int j = 0; j < 8; ++j) acc[j] += c1 * bf2f(h1[j]);
        }
        if (i < re) {
            int idx = i - rs;
            float c0 = __shfl(coef, idx);
            int   s0 = __shfl(s_reg, idx);
            ushort8 h0 = *(const ushort8*)&h[(size_t)s0 * HD + l16 * 8];
#pragma unroll
            for (int j = 0; j < 8; ++j) acc[j] += c0 * bf2f(h0[j]);
        }
    } else {
        float m = -1e30f;
        for (int i = rs + lane; i < re; i += 64) {
            int s = csr_src[i];
            float t0 = alpha_s[s] + ad;
            t0 = (t0 > 0.f) ? t0 : 0.2f * t0;
            m = fmaxf(m, t0);
        }
#pragma unroll
        for (int off = 32; off; off >>= 1) m = fmaxf(m, __shfl_xor(m, off));
        float den = 0.f;
        for (int i = rs + lane; i < re; i += 64) {
            int s = csr_src[i];
            float t0 = alpha_s[s] + ad;
            t0 = (t0 > 0.f) ? t0 : 0.2f * t0;
            den += __expf(t0 - m);
        }
#pragma unroll
        for (int off = 32; off; off >>= 1) den += __shfl_xor(den, off);
        float inv = 1.f / (den + 1e-16f);
        for (int i = rs + grp; i < re; i += 4) {
            int s = csr_src[i];
            float t0 = alpha_s[s] + ad;
            t0 = (t0 > 0.f) ? t0 : 0.2f * t0;
            float c = __expf(t0 - m) * inv;
            ushort8 hv = *(const ushort8*)&h[(size_t)s * HD + l16 * 8];
#pragma unroll
            for (int j = 0; j < 8; ++j) acc[j] += c * bf2f(hv[j]);
        }
    }
#pragma unroll
    for (int j = 0; j < 8; ++j) {
        acc[j] += __shfl_xor(acc[j], 16);
        acc[j] += __shfl_xor(acc[j], 32);
    }
    int f0 = l16 * 8 + grp * 2;
    float2 bv = *(const float2*)&bias[f0];
    float vx = fmaxf(acc[grp * 2]     + bv.x, 0.f);
    float vy = fmaxf(acc[grp * 2 + 1] + bv.y, 0.f);
    unsigned int pv = (unsigned int)f2bf(vx) | ((unsigned int)f2bf(vy) << 16);
    *(unsigned int*)&outp[(size_t)w * HD + f0] = pv;
}

// ---------------- mean pool per graph (bf16 in, 2x node ILP) ----------------

__global__ void pool_kernel(const unsigned short* __restrict__ h, const int* __restrict__ start,
                            float* __restrict__ z) {
    int w = (int)((blockIdx.x * (size_t)blockDim.x + threadIdx.x) >> 6);
    int lane = threadIdx.x & 63;
    if (w >= NB) return;
    int grp = lane >> 4, l16 = lane & 15;
    int s0 = start[w], s1 = start[w + 1];
    float acc[8] = {0.f, 0.f, 0.f, 0.f, 0.f, 0.f, 0.f, 0.f};
    int n = s0 + grp;
    for (; n + 4 < s1; n += 8) {
        ushort8 a = *(const ushort8*)&h[(size_t)n * HD + l16 * 8];
        ushort8 b = *(const ushort8*)&h[(size_t)(n + 4) * HD + l16 * 8];
#pragma unroll
        for (int j = 0; j < 8; ++j) acc[j] += bf2f(a[j]);
#pragma unroll
        for (int j = 0; j < 8; ++j) acc[j] += bf2f(b[j]);
    }
    if (n < s1) {
        ushort8 a = *(const ushort8*)&h[(size_t)n * HD + l16 * 8];
#pragma unroll
        for (int j = 0; j < 8; ++j) acc[j] += bf2f(a[j]);
    }
#pragma unroll
    for (int j = 0; j < 8; ++j) {
        acc[j] += __shfl_xor(acc[j], 16);
        acc[j] += __shfl_xor(acc[j], 32);
    }
    float inv = 1.f / fmaxf((float)(s1 - s0), 1.f);
    int f0 = l16 * 8 + grp * 2;
    *(float2*)&z[(size_t)w * 320 + f0] =
        make_float2(acc[grp * 2] * inv, acc[grp * 2 + 1] * inv);
}

// ---------------- split-K small GEMM with atomic accumulate ----------------

__global__ void gemm_split(const float* __restrict__ X, const float* __restrict__ W1,
                           const float* __restrict__ W2, float* __restrict__ out,
                           int K, int F1, int Ftot, int Kc) {
    __shared__ float Xs[16][33];
    __shared__ float Ws[64][33];
    int t = threadIdx.x;
    int r0 = blockIdx.x * 16;
    int fb = blockIdx.y * 64;
    const float* W = (fb < F1) ? (W1 + (size_t)fb * K) : (W2 + (size_t)(fb - F1) * K);
    int k0 = blockIdx.z * Kc;
    int f = t & 63, rsub = t >> 6;
    float acc0 = 0.f, acc1 = 0.f, acc2 = 0.f, acc3 = 0.f;
    for (int kc = k0; kc < k0 + Kc; kc += 32) {
        {
            int idx = t * 2, xr = idx >> 5, xk = idx & 31;
            const float2 v = *(const float2*)&X[(size_t)(r0 + xr) * K + kc + xk];
            Xs[xr][xk] = v.x; Xs[xr][xk + 1] = v.y;
        }
        {
            int wf = t >> 2, wk = (t & 3) * 8;
            const float4* p = (const float4*)&W[(size_t)wf * K + kc + wk];
            float4 a = p[0], b = p[1];
            Ws[wf][wk] = a.x; Ws[wf][wk + 1] = a.y; Ws[wf][wk + 2] = a.z; Ws[wf][wk + 3] = a.w;
            Ws[wf][wk + 4] = b.x; Ws[wf][wk + 5] = b.y; Ws[wf][wk + 6] = b.z; Ws[wf][wk + 7] = b.w;
        }
        __syncthreads();
#pragma unroll
        for (int k = 0; k < 32; ++k) {
            float w = Ws[f][k];
            acc0 += Xs[rsub][k] * w;
            acc1 += Xs[rsub + 4][k] * w;
            acc2 += Xs[rsub + 8][k] * w;
            acc3 += Xs[rsub + 12][k] * w;
        }
        __syncthreads();
    }
    atomicAdd(&out[(size_t)(r0 + rsub) * Ftot + fb + f], acc0);
    atomicAdd(&out[(size_t)(r0 + rsub + 4) * Ftot + fb + f], acc1);
    atomicAdd(&out[(size_t)(r0 + rsub + 8) * Ftot + fb + f], acc2);
    atomicAdd(&out[(size_t)(r0 + rsub + 12) * Ftot + fb + f], acc3);
}

// ---------------- LSTM nonlinearity ----------------

__device__ __forceinline__ float sigmoidf_(float x) { return 1.f / (1.f + __expf(-x)); }

__global__ void lstm_gate(const float* __restrict__ g,
                          const float* __restrict__ bihf, const float* __restrict__ bhhf,
                          const float* __restrict__ bihr, const float* __restrict__ bhhr,
                          float* __restrict__ z) {
    int idx = blockIdx.x * 256 + threadIdx.x;
    if (idx >= NB * 128) return;
    int b = idx >> 7, jj = idx & 127;
    int dir = jj >> 6, j = jj & 63;
    const float* gb = g + (size_t)b * 512 + dir * 256;
    const float* bi = dir ? bihr : bihf;
    const float* bh = dir ? bhhr : bhhf;
    float gi = gb[j]       + bi[j]       + bh[j];
    float gg = gb[128 + j] + bi[128 + j] + bh[128 + j];
    float go = gb[192 + j] + bi[192 + j] + bh[192 + j];
    float c = sigmoidf_(gi) * tanhf(gg);
    z[(size_t)b * 320 + 128 + jj] = sigmoidf_(go) * tanhf(c);
}

// ---------------- tab branch fused: linear + BN + relu (single block) ----------------

__global__ __launch_bounds__(1024) void tab_fused(const float* __restrict__ tf,
                                                  const float* __restrict__ W,
                                                  const float* __restrict__ bias,
                                                  const float* __restrict__ g,
                                                  const float* __restrict__ b,
                                                  float* __restrict__ z) {
    __shared__ float ssum[16][64];
    __shared__ float ssq[16][64];
    int t = threadIdx.x;
    int rg = t >> 6, j = t & 63;
    float Wj[7];
#pragma unroll
    for (int k = 0; k < 7; ++k) Wj[k] = W[j * 7 + k];
    float bj = bias[j];
    float pre[64];
    float s = 0.f, q = 0.f;
    for (int rr = 0; rr < 64; ++rr) {
        int row = rg * 64 + rr;
        const float* x = &tf[(size_t)row * 7];
        float a = bj;
#pragma unroll
        for (int k = 0; k < 7; ++k) a += x[k] * Wj[k];
        pre[rr] = a; s += a; q += a * a;
    }
    ssum[rg][j] = s; ssq[rg][j] = q;
    __syncthreads();
    for (int off = 8; off; off >>= 1) {
        if (rg < off) { ssum[rg][j] += ssum[rg + off][j]; ssq[rg][j] += ssq[rg + off][j]; }
        __syncthreads();
    }
    float mu = ssum[0][j] * (1.f / 1024.f);
    float var = ssq[0][j] * (1.f / 1024.f) - mu * mu;
    float sc = rsqrtf(var + 1e-5f) * g[j];
    float bb = b[j] - mu * sc;
    for (int rr = 0; rr < 64; ++rr) {
        int row = rg * 64 + rr;
        z[(size_t)row * 320 + 256 + j] = fmaxf(pre[rr] * sc + bb, 0.f);
    }
}

// ---------------- BatchNorm (training stats) + relu ----------------

__global__ void bn_relu_cols(const float* __restrict__ in, int cols,
                             const float* __restrict__ g, const float* __restrict__ b,
                             float* __restrict__ out, int out_stride, int out_col0) {
    int j = blockIdx.x;
    int t = threadIdx.x;
    __shared__ float ssum[256], ssq[256];
    float vals[4];
    float s = 0.f, q = 0.f;
#pragma unroll
    for (int i = 0; i < 4; ++i) {
        float v = in[(size_t)(t + 256 * i) * cols + j];
        vals[i] = v; s += v; q += v * v;
    }
    ssum[t] = s; ssq[t] = q;
    __syncthreads();
    for (int off = 128; off; off >>= 1) {
        if (t < off) { ssum[t] += ssum[t + off]; ssq[t] += ssq[t + off]; }
        __syncthreads();
    }
    float mu = ssum[0] * (1.f / 1024.f);
    float var = ssq[0] * (1.f / 1024.f) - mu * mu;
    float sc = rsqrtf(var + 1e-5f) * g[j];
    float bb = b[j] - mu * sc;
#pragma unroll
    for (int i = 0; i < 4; ++i) {
        float v = vals[i] * sc + bb;
        out[(size_t)(t + 256 * i) * out_stride + out_col0 + j] = fmaxf(v, 0.f);
    }
}

// ---------------- final: relu(z2 + b2) @ fus3_W^T + fus3_b ----------------

__global__ void final_kernel(const float* __restrict__ z2, const float* __restrict__ b2,
                             const float* __restrict__ W, const float* __restrict__ b,
                             float* __restrict__ out) {
    int w = (int)((blockIdx.x * (size_t)blockDim.x + threadIdx.x) >> 6);
    int lane = threadIdx.x & 63;
    if (w >= NB) return;
    float2 zv = *(const float2*)&z2[(size_t)w * 128 + lane * 2];
    float2 bv = *(const float2*)&b2[lane * 2];
    float2 wv = *(const float2*)&W[lane * 2];
    float zx = fmaxf(zv.x + bv.x, 0.f);
    float zy = fmaxf(zv.y + bv.y, 0.f);
    float s = zx * wv.x + zy * wv.y;
    for (int off = 32; off; off >>= 1) s += __shfl_down(s, off);
    if (lane == 0) out[w] = s + b[0];
}

// ---------------- launch ----------------

extern "C" void kernel_launch(void* const* d_in, const int* in_sizes, int n_in,
                              void* d_out, int out_size, void* d_ws, size_t ws_size,
                              hipStream_t stream) {
    const float* x        = (const float*)d_in[0];
    const int*   ei       = (const int*)d_in[1];
    const int*   batch    = (const int*)d_in[2];
    const float* esm      = (const float*)d_in[3];
    const float* tabf     = (const float*)d_in[4];
    const float* gat1_W   = (const float*)d_in[5];
    const float* gat1_as  = (const float*)d_in[6];
    const float* gat1_ad  = (const float*)d_in[7];
    const float* gat1_b   = (const float*)d_in[8];
    const float* gat2_W   = (const float*)d_in[9];
    const float* gat2_as  = (const float*)d_in[10];
    const float* gat2_ad  = (const float*)d_in[11];
    const float* gat2_b   = (const float*)d_in[12];
    const float* Wih_f    = (const float*)d_in[13];
    const float* bih_f    = (const float*)d_in[15];
    const float* bhh_f    = (const float*)d_in[16];
    const float* Wih_r    = (const float*)d_in[17];
    const float* bih_r    = (const float*)d_in[19];
    const float* bhh_r    = (const float*)d_in[20];
    const float* tab_W    = (const float*)d_in[21];
    const float* tab_b    = (const float*)d_in[22];
    const float* tab_g    = (const float*)d_in[23];
    const float* tab_bb   = (const float*)d_in[24];
    const float* fus1_W   = (const float*)d_in[25];
    const float* fus_g    = (const float*)d_in[27];
    const float* fus_bb   = (const float*)d_in[28];
    const float* fus2_W   = (const float*)d_in[29];
    const float* fus2_b   = (const float*)d_in[30];
    const float* fus3_W   = (const float*)d_in[31];
    const float* fus3_b   = (const float*)d_in[32];
    float* out = (float*)d_out;

    char* ws = (char*)d_ws;
    size_t off = 0;
    auto alloc = [&](size_t bytes) -> char* {
        char* p = ws + off;
        off += (bytes + 255) & ~(size_t)255;
        return p;
    };
    unsigned short* h0_bf = (unsigned short*)alloc((size_t)N_PAD * HD * 2);
    unsigned short* hA_bf = (unsigned short*)alloc((size_t)N_PAD * HD * 2);
    unsigned short* h2_bf = (unsigned short*)alloc((size_t)N_PAD * HD * 2);
    unsigned short* h_act = (unsigned short*)alloc((size_t)N_NODES * HD * 2);
    float* alpha_s = (float*)alloc((size_t)N_NODES * 4);
    float* alpha_d = (float*)alloc((size_t)N_NODES * 4);
    unsigned short* w2bf = (unsigned short*)alloc((size_t)HD * HD * 2);
    int*   row_ptr = (int*)alloc((size_t)(N_NODES + 1) * 4);
    int*   csr_src = (int*)alloc((size_t)E_TOT * 4);
    int*   pairs   = (int*)alloc((size_t)E_TOT * 4);
    int*   cnt     = (int*)alloc((size_t)NBUCK * 256 * 4);
    int*   cntoff  = (int*)alloc((size_t)NBUCK * 256 * 4);
    int*   gstart  = (int*)alloc((size_t)(NB + 1) * 4);
    float* z       = (float*)alloc((size_t)NB * 320 * 4);
    float* z1      = (float*)alloc((size_t)NB * 256 * 4);
    // zero-init group (contiguous, one memset)
    float* g_lstm  = (float*)alloc((size_t)NB * 512 * 4);
    float* z1pre   = (float*)alloc((size_t)NB * 256 * 4);
    float* z2      = (float*)alloc((size_t)NB * 128 * 4);
    size_t zero_len = (size_t)((char*)z2 + (size_t)NB * 128 * 4 - (char*)g_lstm);
    hipMemsetAsync(g_lstm, 0, zero_len, stream);

    // CSR build (bucketed counting sort, no global atomics)
    hist1<<<256, 256, 0, stream>>>(ei, cnt);
    scan4<<<1, 1024, 0, stream>>>((const int4*)cnt, (int4*)cntoff, NBUCK * 64);
    scatter_pairs<<<256, 256, 0, stream>>>(ei, cntoff, pairs);
    bucket_csr<<<NBUCK, 256, 0, stream>>>(cntoff, pairs, row_ptr, csr_src);
    bounds_conv<<<NBUCK + 16, 256, 0, stream>>>(batch, gstart, gat2_W, w2bf);

    int aggGrid = (N_NODES + 3) / 4;

    // GAT layer 1 (alphas fused into linear)
    matmul_gat1<<<(N_NODES + 31) / 32, 256, 0, stream>>>(x, gat1_W, gat1_as, gat1_ad,
                                                          h0_bf, alpha_s, alpha_d);
    gat_spmm<<<aggGrid, 256, 0, stream>>>(h0_bf, row_ptr, csr_src, alpha_s, alpha_d,
                                          gat1_b, hA_bf);

    // GAT layer 2 (alphas fused into MFMA epilogue)
    gemm_mfma<<<N_PAD / 64, 256, 0, stream>>>(hA_bf, w2bf, gat2_as, gat2_ad,
                                              h2_bf, alpha_s, alpha_d, N_NODES);
    gat_spmm<<<aggGrid, 256, 0, stream>>>(h2_bf, row_ptr, csr_src, alpha_s, alpha_d,
                                          gat2_b, h_act);

    // mean pool -> z[:, 0:128)
    pool_kernel<<<(NB + 3) / 4, 256, 0, stream>>>(h_act, gstart, z);

    // LSTM gates (f+r fused)
    gemm_split<<<dim3(64, 8, 3), 256, 0, stream>>>(esm, Wih_f, Wih_r, g_lstm, ESM_DIM, 256, 512, 160);
    lstm_gate<<<(NB * 128 + 255) / 256, 256, 0, stream>>>(g_lstm, bih_f, bhh_f, bih_r, bhh_r, z);

    // tab branch (fused linear+BN+relu, single block)
    tab_fused<<<1, 1024, 0, stream>>>(tabf, tab_W, tab_b, tab_g, tab_bb, z);

    // fusion head
    gemm_split<<<dim3(64, 4, 2), 256, 0, stream>>>(z, fus1_W, nullptr, z1pre, 320, 256, 256, 160);
    bn_relu_cols<<<256, 256, 0, stream>>>(z1pre, 256, fus_g, fus_bb, z1, 256, 0);
    gemm_split<<<dim3(64, 2, 2), 256, 0, stream>>>(z1, fus2_W, nullptr, z2, 256, 128, 128, 128);
    final_kernel<<<(NB + 3) / 4, 256, 0, stream>>>(z2, fus2_b, fus3_W, fus3_b, out);

    (void)in_sizes; (void)n_in; (void)out_size; (void)ws_size;
}